// Round 15
// baseline (699.073 us; speedup 1.0000x reference)
//
#include <hip/hip_runtime.h>
#include <hip/hip_cooperative_groups.h>

namespace cg = cooperative_groups;

#define D 128
#define KNOW 1024
#define ITEM 20000
#define NTOT (ITEM + KNOW)
#define LAYERS 2
#define LAT 256
#define BB 256
#define SS 200
#define H3 (3 * D)
#define CH 8
#define ZROWS 64
#define NBK (KNOW / ZROWS)                 // 16
#define NBN ((NTOT + ZROWS - 1) / ZROWS)   // 329
#define NZT (NBK + 2 * NBN)                // 674 zdv tiles
#define NAGGU (KNOW / 4 + ITEM / 4)        // 5256 agg units
#define NKROW (BB * CH)                    // 2048 krowk units
#define XPITCH 68
#define MGRID 256

// ---------------- zdv tile (device fn): z = X@W + dvec for one 64-row tile ----------------
__device__ __forceinline__ void zdv_tile(int bid, int layer, float* __restrict__ xT,
    const float* __restrict__ Xe, const float* __restrict__ Xk,
    const float* __restrict__ gW, const float* __restrict__ gA,
    float* __restrict__ z1, float* __restrict__ z2, float* __restrict__ z3,
    float* __restrict__ ds1, float* __restrict__ dd1,
    float* __restrict__ ds2, float* __restrict__ dd2,
    float* __restrict__ ds3, float* __restrict__ dd3)
{
    int g, row0, nmax;
    if (bid < NBK)            { g = 0; row0 = bid * ZROWS;                nmax = KNOW; }
    else if (bid < NBK + NBN) { g = 1; row0 = (bid - NBK) * ZROWS;        nmax = NTOT; }
    else                      { g = 2; row0 = (bid - NBK - NBN) * ZROWS;  nmax = NTOT; }
    const float* W = gW + (size_t)(layer * 3 + g) * D * D;
    const float* A = gA + (size_t)(layer * 3 + g) * 2 * D;
    float* Z  = (g == 0) ? z1  : (g == 1 ? z2  : z3);
    float* DS = (g == 0) ? ds1 : (g == 1 ? ds2 : ds3);
    float* DD = (g == 0) ? dd1 : (g == 1 ? dd2 : dd3);

    int tid = threadIdx.x;
    __syncthreads();   // previous tile's readers done before overwriting xT
#pragma unroll
    for (int i = 0; i < 8; ++i) {
        int flat = tid + i * 256;
        int row  = flat >> 5;
        int f4   = flat & 31;
        int grow = row0 + row;
        float4 v = make_float4(0.f, 0.f, 0.f, 0.f);
        if (grow < nmax) {
            const float* src = (g == 0) ? (Xk + (size_t)grow * D)
                             : (grow < ITEM ? Xe + (size_t)grow * D
                                            : Xk + (size_t)(grow - ITEM) * D);
            v = *(const float4*)(src + f4 * 4);
        }
        int slot = row ^ ((f4 & 7) << 2);
        int kk = f4 * 4;
        xT[(kk + 0) * XPITCH + slot] = v.x;
        xT[(kk + 1) * XPITCH + slot] = v.y;
        xT[(kk + 2) * XPITCH + slot] = v.z;
        xT[(kk + 3) * XPITCH + slot] = v.w;
    }
    __syncthreads();

    int cg_ = tid & 31;
    int rg = tid >> 5;
    int c0 = cg_ * 4;
    int r0a = rg * 8, r0b = rg * 8 + 4;

    float acc[8][4];
#pragma unroll
    for (int r = 0; r < 8; ++r)
#pragma unroll
        for (int c = 0; c < 4; ++c) acc[r][c] = 0.f;

#pragma unroll 4
    for (int k = 0; k < D; ++k) {
        float4 wv = *(const float4*)(W + (size_t)k * D + c0);
        int xc = ((k >> 2) & 7) << 2;
        float4 xa = *(const float4*)&xT[k * XPITCH + (r0a ^ xc)];
        float4 xb = *(const float4*)&xT[k * XPITCH + (r0b ^ xc)];
        acc[0][0] = fmaf(xa.x, wv.x, acc[0][0]); acc[0][1] = fmaf(xa.x, wv.y, acc[0][1]);
        acc[0][2] = fmaf(xa.x, wv.z, acc[0][2]); acc[0][3] = fmaf(xa.x, wv.w, acc[0][3]);
        acc[1][0] = fmaf(xa.y, wv.x, acc[1][0]); acc[1][1] = fmaf(xa.y, wv.y, acc[1][1]);
        acc[1][2] = fmaf(xa.y, wv.z, acc[1][2]); acc[1][3] = fmaf(xa.y, wv.w, acc[1][3]);
        acc[2][0] = fmaf(xa.z, wv.x, acc[2][0]); acc[2][1] = fmaf(xa.z, wv.y, acc[2][1]);
        acc[2][2] = fmaf(xa.z, wv.z, acc[2][2]); acc[2][3] = fmaf(xa.z, wv.w, acc[2][3]);
        acc[3][0] = fmaf(xa.w, wv.x, acc[3][0]); acc[3][1] = fmaf(xa.w, wv.y, acc[3][1]);
        acc[3][2] = fmaf(xa.w, wv.z, acc[3][2]); acc[3][3] = fmaf(xa.w, wv.w, acc[3][3]);
        acc[4][0] = fmaf(xb.x, wv.x, acc[4][0]); acc[4][1] = fmaf(xb.x, wv.y, acc[4][1]);
        acc[4][2] = fmaf(xb.x, wv.z, acc[4][2]); acc[4][3] = fmaf(xb.x, wv.w, acc[4][3]);
        acc[5][0] = fmaf(xb.y, wv.x, acc[5][0]); acc[5][1] = fmaf(xb.y, wv.y, acc[5][1]);
        acc[5][2] = fmaf(xb.y, wv.z, acc[5][2]); acc[5][3] = fmaf(xb.y, wv.w, acc[5][3]);
        acc[6][0] = fmaf(xb.z, wv.x, acc[6][0]); acc[6][1] = fmaf(xb.z, wv.y, acc[6][1]);
        acc[6][2] = fmaf(xb.z, wv.z, acc[6][2]); acc[6][3] = fmaf(xb.z, wv.w, acc[6][3]);
        acc[7][0] = fmaf(xb.w, wv.x, acc[7][0]); acc[7][1] = fmaf(xb.w, wv.y, acc[7][1]);
        acc[7][2] = fmaf(xb.w, wv.z, acc[7][2]); acc[7][3] = fmaf(xb.w, wv.w, acc[7][3]);
    }

#pragma unroll
    for (int r = 0; r < 8; ++r) {
        int grow = row0 + ((r < 4) ? (r0a + r) : (r0b + r - 4));
        if (grow < nmax) {
            float4 v = make_float4(acc[r][0], acc[r][1], acc[r][2], acc[r][3]);
            *(float4*)(Z + (size_t)grow * D + c0) = v;
        }
    }

    float4 as = *(const float4*)(A + c0);
    float4 ad = *(const float4*)(A + D + c0);
    float ps[8], pd[8];
#pragma unroll
    for (int r = 0; r < 8; ++r) {
        ps[r] = acc[r][0] * as.x + acc[r][1] * as.y + acc[r][2] * as.z + acc[r][3] * as.w;
        pd[r] = acc[r][0] * ad.x + acc[r][1] * ad.y + acc[r][2] * ad.z + acc[r][3] * ad.w;
    }
#pragma unroll
    for (int m = 16; m; m >>= 1) {
#pragma unroll
        for (int r = 0; r < 8; ++r) {
            ps[r] += __shfl_xor(ps[r], m, 64);
            pd[r] += __shfl_xor(pd[r], m, 64);
        }
    }
    if (cg_ == 0) {
#pragma unroll
        for (int r = 0; r < 8; ++r) {
            int grow = row0 + ((r < 4) ? (r0a + r) : (r0b + r - 4));
            if (grow < nmax) { DS[grow] = ps[r]; DD[grow] = pd[r]; }
        }
    }
}

// ---------------- per-row attention aggregation, 4-way edge-parallel ----------------
__device__ __forceinline__ void agg_row(const float* __restrict__ Z, const float* __restrict__ dsrc,
                                        float dd, const int* __restrict__ es, int e0, int e1,
                                        int lane, float* __restrict__ acc) {
#pragma unroll
    for (int q = 0; q < 8; ++q) acc[q] = 0.f;
    if (e1 <= e0) return;
    float mx = -3.4e38f;
    for (int e = e0 + lane; e < e1; e += 64) {
        float t = dsrc[es[e]] + dd;
        t = (t > 0.f) ? t : 0.01f * t;
        mx = fmaxf(mx, t);
    }
#pragma unroll
    for (int o = 32; o; o >>= 1) mx = fmaxf(mx, __shfl_xor(mx, o, 64));
    int eg = lane >> 4, cs = lane & 15;
    float den = 0.f;
    for (int e = e0 + eg; e < e1; e += 4) {
        int s = es[e];
        float t = dsrc[s] + dd;
        t = (t > 0.f) ? t : 0.01f * t;
        float w = __expf(t - mx);
        den += w;
        const float4* zr = (const float4*)(Z + (size_t)s * D + cs * 8);
        float4 za = zr[0], zb = zr[1];
        acc[0] = fmaf(w, za.x, acc[0]); acc[1] = fmaf(w, za.y, acc[1]);
        acc[2] = fmaf(w, za.z, acc[2]); acc[3] = fmaf(w, za.w, acc[3]);
        acc[4] = fmaf(w, zb.x, acc[4]); acc[5] = fmaf(w, zb.y, acc[5]);
        acc[6] = fmaf(w, zb.z, acc[6]); acc[7] = fmaf(w, zb.w, acc[7]);
    }
#pragma unroll
    for (int m = 16; m <= 32; m <<= 1) {
        den += __shfl_xor(den, m, 64);
#pragma unroll
        for (int q = 0; q < 8; ++q) acc[q] += __shfl_xor(acc[q], m, 64);
    }
    float inv = 1.f / fmaxf(den, 1e-12f);
#pragma unroll
    for (int q = 0; q < 8; ++q) acc[q] *= inv;
}

// ---------------- agg unit (device fn): paired kdir/kfe + combine, or graph3 row ----------------
__device__ __forceinline__ void agg_unit(int u, float (*ABs)[2][D],
    const float* __restrict__ z1, const float* __restrict__ z2, const float* __restrict__ z3,
    const float* __restrict__ ds1, const float* __restrict__ dd1,
    const float* __restrict__ ds2, const float* __restrict__ dd2,
    const float* __restrict__ ds3, const float* __restrict__ dd3,
    const int* __restrict__ off1, const int* __restrict__ es1,
    const int* __restrict__ off2, const int* __restrict__ es2,
    const int* __restrict__ off3, const int* __restrict__ es3,
    const float* __restrict__ raW1L, const float* __restrict__ raB1L,
    const float* __restrict__ raW2L, float* __restrict__ buf)
{
    int wv = threadIdx.x >> 6, lane = threadIdx.x & 63;
    int eg = lane >> 4, cs = lane & 15;
    if (u < KNOW / 4) {
        __syncthreads();   // ABs reuse guard
        int i = u * 4 + wv;
        float accA[8], accB[8];
        agg_row(z1, ds1, dd1[i], es1, off1[i], off1[i + 1], lane, accA);
        agg_row(z2, ds2, dd2[ITEM + i], es2, off2[i], off2[i + 1], lane, accB);
        if (eg == 0) {
            *(float4*)&ABs[wv][0][cs * 8]     = make_float4(accA[0], accA[1], accA[2], accA[3]);
            *(float4*)&ABs[wv][0][cs * 8 + 4] = make_float4(accA[4], accA[5], accA[6], accA[7]);
            *(float4*)&ABs[wv][1][cs * 8]     = make_float4(accB[0], accB[1], accB[2], accB[3]);
            *(float4*)&ABs[wv][1][cs * 8 + 4] = make_float4(accB[4], accB[5], accB[6], accB[7]);
        }
        __syncthreads();
        int j0 = lane * 2;
        float b0 = raB1L[j0], b1 = raB1L[j0 + 1];
        float aA0 = b0, aA1 = b1, aB0 = b0, aB1 = b1;
#pragma unroll 4
        for (int k = 0; k < D; ++k) {
            float av = ABs[wv][0][k], bv = ABs[wv][1][k];
            float2 w = *(const float2*)(raW1L + (size_t)k * D + j0);
            aA0 = fmaf(av, w.x, aA0); aA1 = fmaf(av, w.y, aA1);
            aB0 = fmaf(bv, w.x, aB0); aB1 = fmaf(bv, w.y, aB1);
        }
        float2 w2 = *(const float2*)(raW2L + j0);
        float pA = tanhf(aA0) * w2.x + tanhf(aA1) * w2.y;
        float pB = tanhf(aB0) * w2.x + tanhf(aB1) * w2.y;
#pragma unroll
        for (int o = 32; o; o >>= 1) { pA += __shfl_xor(pA, o, 64); pB += __shfl_xor(pB, o, 64); }
        float mx2 = fmaxf(pA, pB);
        float eA = __expf(pA - mx2), eB = __expf(pB - mx2);
        float s = 1.f / (eA + eB);
        float sA = eA * s, sB = eB * s;
        float2 Av = *(float2*)&ABs[wv][0][j0];
        float2 Bv = *(float2*)&ABs[wv][1][j0];
        *(float2*)(buf + (size_t)(ITEM + i) * D + j0) =
            make_float2(sA * Av.x + sB * Bv.x, sA * Av.y + sB * Bv.y);
    } else {
        int row = (u - KNOW / 4) * 4 + wv;
        if (row < ITEM) {
            float acc[8];
            agg_row(z3, ds3, dd3[row], es3, off3[row], off3[row + 1], lane, acc);
            if (eg == 0) {
                *(float4*)(buf + (size_t)row * D + cs * 8)     = make_float4(acc[0], acc[1], acc[2], acc[3]);
                *(float4*)(buf + (size_t)row * D + cs * 8 + 4) = make_float4(acc[4], acc[5], acc[6], acc[7]);
            }
        }
    }
}

// ---------------- krowk unit (device fn) ----------------
__device__ __forceinline__ void krow_unit(int uk, const float* __restrict__ kn_rec,
                                          const float* __restrict__ kn_num,
                                          const int* __restrict__ p_target, float* __restrict__ krowP)
{
    int b = uk & (BB - 1), ch = uk >> 8;
    int cnt = p_target[b] + 1;
    int per = (SS + CH - 1) / CH;
    int s0 = ch * per, s1 = s0 + per;
    if (s1 > cnt) s1 = cnt;
    int k0 = threadIdx.x * 4;
    float4 a = make_float4(0.f, 0.f, 0.f, 0.f);
    for (int s = s0; s < s1; ++s) {
        float inv = 1.f / kn_num[b * SS + s];
        float4 v = *(const float4*)(kn_rec + ((size_t)b * SS + s) * KNOW + k0);
        a.x += v.x * inv; a.y += v.y * inv; a.z += v.z * inv; a.w += v.w * inv;
    }
    *(float4*)(krowP + ((size_t)ch * BB + b) * KNOW + k0) = a;
}

// ---------------- cooperative mega-kernel: [zdv -> agg(+krowk)] x 2 layers ----------------
__global__ __launch_bounds__(256) void megaker(
    const float* Xe0, const float* Xk0, const float* gW, const float* gA,
    float* buf, float* z1, float* z2, float* z3,
    float* ds1, float* dd1, float* ds2, float* dd2, float* ds3, float* dd3,
    const int* off1, const int* es1, const int* off2, const int* es2,
    const int* off3, const int* es3,
    const float* raW1, const float* raB1, const float* raW2,
    const float* kn_rec, const float* kn_num, const int* p_target, float* krowP)
{
    cg::grid_group grid = cg::this_grid();
    __shared__ __align__(16) float xT[D * XPITCH];     // 34.8 KB
    __shared__ float ABs[4][2][D];                      // 4 KB
    for (int l = 0; l < LAYERS; ++l) {
        const float* Xe = (l == 0) ? Xe0 : buf;
        const float* Xk = (l == 0) ? Xk0 : (buf + (size_t)ITEM * D);
        for (int t = blockIdx.x; t < NZT; t += MGRID)
            zdv_tile(t, l, xT, Xe, Xk, gW, gA, z1, z2, z3, ds1, dd1, ds2, dd2, ds3, dd3);
        grid.sync();
        int nu = NAGGU + ((l == 0) ? NKROW : 0);
        for (int u = blockIdx.x; u < nu; u += MGRID) {
            if (u < NAGGU)
                agg_unit(u, ABs, z1, z2, z3, ds1, dd1, ds2, dd2, ds3, dd3,
                         off1, es1, off2, es2, off3, es3,
                         raW1 + (size_t)l * D * D, raB1 + (size_t)l * D, raW2 + (size_t)l * D, buf);
            else
                krow_unit(u - NAGGU, kn_rec, kn_num, p_target, krowP);
        }
        grid.sync();
    }
}

// ---------------- fallback wrappers (separate launches, known-good R13 path) ----------------
__global__ __launch_bounds__(256) void zdv_ker(
    const float* __restrict__ Xe, const float* __restrict__ Xk,
    const float* __restrict__ gW, const float* __restrict__ gA, int layer,
    float* __restrict__ z1, float* __restrict__ z2, float* __restrict__ z3,
    float* __restrict__ ds1, float* __restrict__ dd1,
    float* __restrict__ ds2, float* __restrict__ dd2,
    float* __restrict__ ds3, float* __restrict__ dd3)
{
    __shared__ __align__(16) float xT[D * XPITCH];
    zdv_tile(blockIdx.x, layer, xT, Xe, Xk, gW, gA, z1, z2, z3, ds1, dd1, ds2, dd2, ds3, dd3);
}

__global__ __launch_bounds__(256) void agg3c_ker(
    const float* __restrict__ z1, const float* __restrict__ z2, const float* __restrict__ z3,
    const float* __restrict__ ds1, const float* __restrict__ dd1,
    const float* __restrict__ ds2, const float* __restrict__ dd2,
    const float* __restrict__ ds3, const float* __restrict__ dd3,
    const int* __restrict__ off1, const int* __restrict__ es1,
    const int* __restrict__ off2, const int* __restrict__ es2,
    const int* __restrict__ off3, const int* __restrict__ es3,
    const float* __restrict__ raW1L, const float* __restrict__ raB1L,
    const float* __restrict__ raW2L, float* __restrict__ buf)
{
    __shared__ float ABs[4][2][D];
    agg_unit(blockIdx.x, ABs, z1, z2, z3, ds1, dd1, ds2, dd2, ds3, dd3,
             off1, es1, off2, es2, off3, es3, raW1L, raB1L, raW2L, buf);
}

__global__ __launch_bounds__(256) void krowk_ker(const float* __restrict__ kn_rec,
                                                 const float* __restrict__ kn_num,
                                                 const int* __restrict__ p_target,
                                                 float* __restrict__ krowP) {
    krow_unit(blockIdx.y * BB + blockIdx.x, kn_rec, kn_num, p_target, krowP);
}

// ---------------- CSR build ----------------
__global__ void hist3(const int* __restrict__ d1, const int* __restrict__ d2, const int* __restrict__ d3,
                      int E1, int E2, int* __restrict__ c1, int* __restrict__ c2, int* __restrict__ c3) {
    int i = blockIdx.x * blockDim.x + threadIdx.x;
    if (i < E1) atomicAdd(&c1[d1[i]], 1);
    else if (i < E1 + E2) { int d = d2[i - E1]; if (d >= ITEM) atomicAdd(&c2[d - ITEM], 1); }
    else if (i < E1 + 2 * E2) { int d = d3[i - E1 - E2]; if (d < ITEM) atomicAdd(&c3[d], 1); }
}

__global__ __launch_bounds__(1024) void exscan3(int* __restrict__ c1, int* __restrict__ o1,
                                                int* __restrict__ c2, int* __restrict__ o2,
                                                int* __restrict__ c3, int* __restrict__ o3) {
    int g = blockIdx.x;
    int* cnt = (g == 0) ? c1 : (g == 1 ? c2 : c3);
    int* off = (g == 0) ? o1 : (g == 1 ? o2 : o3);
    int n = (g == 2) ? ITEM : KNOW;
    int tid = threadIdx.x, lane = tid & 63, wid = tid >> 6;
    int L = (n + 1023) >> 10;
    int i0 = tid * L;
    int sum = 0;
    for (int q = 0; q < L; ++q) {
        int i = i0 + q;
        if (i < n) sum += cnt[i];
    }
    int x = sum;
#pragma unroll
    for (int d = 1; d < 64; d <<= 1) { int t = __shfl_up(x, d, 64); if (lane >= d) x += t; }
    __shared__ int ws[16];
    if (lane == 63) ws[wid] = x;
    __syncthreads();
    if (wid == 0) {
        int w = (lane < 16) ? ws[lane] : 0;
#pragma unroll
        for (int d = 1; d < 16; d <<= 1) { int t = __shfl_up(w, d, 64); if (lane >= d) w += t; }
        if (lane < 16) ws[lane] = w;
    }
    __syncthreads();
    int run = x - sum + ((wid > 0) ? ws[wid - 1] : 0);
    if (tid == 0) off[0] = 0;
    for (int q = 0; q < L; ++q) {
        int i = i0 + q;
        if (i < n) {
            int v = cnt[i];
            cnt[i] = run;
            run += v;
            off[i + 1] = run;
        }
    }
}

__global__ void scatter3(const int* __restrict__ s1, const int* __restrict__ d1,
                         const int* __restrict__ s2, const int* __restrict__ d2,
                         const int* __restrict__ s3, const int* __restrict__ d3,
                         int E1, int E2, int* __restrict__ cur1, int* __restrict__ cur2, int* __restrict__ cur3,
                         int* __restrict__ e1, int* __restrict__ e2, int* __restrict__ e3) {
    int i = blockIdx.x * blockDim.x + threadIdx.x;
    if (i < E1) { int p = atomicAdd(&cur1[d1[i]], 1); e1[p] = s1[i]; }
    else if (i < E1 + E2) { int j = i - E1; int d = d2[j]; if (d >= ITEM) { int p = atomicAdd(&cur2[d - ITEM], 1); e2[p] = s2[j]; } }
    else if (i < E1 + 2 * E2) { int j = i - E1 - E2; int d = d3[j]; if (d < ITEM) { int p = atomicAdd(&cur3[d], 1); e3[p] = s3[j]; } }
}

// ---------------- h assembly ----------------
__global__ __launch_bounds__(512) void hker(const float* __restrict__ ex, const float* __restrict__ ans_table,
                                            const int* __restrict__ p_rec, const int* __restrict__ a_rec,
                                            const int* __restrict__ p_target, const float* __restrict__ krowP,
                                            const float* __restrict__ kn, float* __restrict__ h) {
    int b = blockIdx.x;
    int j = threadIdx.x & 127, sg = threadIdx.x >> 7;
    int cnt = p_target[b] + 1;
    __shared__ int pidx[SS], aidx[SS];
    __shared__ float kr[KNOW];
    __shared__ float red[4][3][128];
    for (int i = threadIdx.x; i < cnt; i += 512) { pidx[i] = p_rec[b * SS + i]; aidx[i] = a_rec[b * SS + i]; }
    for (int i = threadIdx.x; i < KNOW; i += 512) {
        float s = 0.f;
#pragma unroll
        for (int c = 0; c < CH; ++c) s += krowP[((size_t)c * BB + b) * KNOW + i];
        kr[i] = s;
    }
    __syncthreads();
    float accE = 0.f, accA = 0.f;
    for (int s = sg; s < cnt; s += 4) {
        accE += ex[(size_t)pidx[s] * D + j];
        accA += ans_table[aidx[s] * D + j];
    }
    float accK = 0.f;
    for (int k = sg * 256; k < sg * 256 + 256; ++k) accK += kr[k] * kn[(size_t)k * D + j];
    red[sg][0][j] = accE; red[sg][1][j] = accA; red[sg][2][j] = accK;
    __syncthreads();
    if (sg == 0) {
        float inv = 1.f / (float)cnt;
        float e = (red[0][0][j] + red[1][0][j] + red[2][0][j] + red[3][0][j]) * inv;
        float a = (red[0][1][j] + red[1][1][j] + red[2][1][j] + red[3][1][j]) * inv;
        float kv = (red[0][2][j] + red[1][2][j] + red[2][2][j] + red[3][2][j]) * inv;
        h[b * H3 + j] = e;
        h[b * H3 + D + j] = a;
        h[b * H3 + 2 * D + j] = kv;
    }
}

// ---------------- unified hidden GEMM ----------------
__global__ __launch_bounds__(256) void hidden_gemm(const float* __restrict__ h,
                                                   const float* __restrict__ actW1, const float* __restrict__ actB1,
                                                   const float* __restrict__ vW1, const float* __restrict__ vB1,
                                                   float* __restrict__ hid) {
    __shared__ float hT[H3 * 17];
    int tid = threadIdx.x;
    int b0 = blockIdx.y * 16;
    for (int idx = tid; idx < 16 * H3; idx += 256) {
        int r = idx / H3, k = idx - r * H3;
        hT[k * 17 + r] = h[(size_t)(b0 + r) * H3 + k];
    }
    __syncthreads();
    int j = blockIdx.x * 64 + (tid & 63);
    int head = j >> 8, jj = j & 255;
    int rg = tid >> 6, r0 = rg * 4;
    const float* W = (head == 0) ? actW1 : (vW1 + (size_t)(head - 1) * H3 * LAT);
    float bias = (head == 0) ? actB1[jj] : vB1[(head - 1) * LAT + jj];
    float acc[4] = {bias, bias, bias, bias};
#pragma unroll 4
    for (int k = 0; k < H3; ++k) {
        float w = W[(size_t)k * LAT + jj];
        float h0 = hT[k * 17 + r0 + 0];
        float h1 = hT[k * 17 + r0 + 1];
        float h2 = hT[k * 17 + r0 + 2];
        float h3 = hT[k * 17 + r0 + 3];
        acc[0] = fmaf(h0, w, acc[0]);
        acc[1] = fmaf(h1, w, acc[1]);
        acc[2] = fmaf(h2, w, acc[2]);
        acc[3] = fmaf(h3, w, acc[3]);
    }
#pragma unroll
    for (int r = 0; r < 4; ++r)
        hid[((size_t)head * BB + (b0 + r0 + r)) * LAT + jj] = tanhf(acc[r]);
}

// ---------------- logits GEMM ----------------
__global__ __launch_bounds__(256) void logitsker(const float* __restrict__ hid, const float* __restrict__ actW2,
                                                 const float* __restrict__ actB2, float* __restrict__ out) {
    __shared__ float hT[LAT * 33];
    int tid = threadIdx.x;
    int b0 = blockIdx.y * 32;
    for (int idx = tid; idx < 32 * LAT; idx += 256) {
        int r = idx >> 8, k = idx & 255;
        hT[k * 33 + r] = hid[(size_t)(b0 + r) * LAT + k];
    }
    __syncthreads();
    int lane6 = tid & 63;
    int rg = tid >> 6, r0 = rg * 8;
    int ibase = blockIdx.x * 256 + lane6;
    int icol[4], icl[4];
    float bias[4];
#pragma unroll
    for (int c = 0; c < 4; ++c) {
        icol[c] = ibase + c * 64;
        icl[c] = icol[c] < ITEM ? icol[c] : (ITEM - 1);
        bias[c] = actB2[icl[c]];
    }
    float acc[8][4];
#pragma unroll
    for (int r = 0; r < 8; ++r)
#pragma unroll
        for (int c = 0; c < 4; ++c) acc[r][c] = bias[c];
#pragma unroll 2
    for (int k = 0; k < LAT; ++k) {
        float w0 = actW2[(size_t)k * ITEM + icl[0]];
        float w1 = actW2[(size_t)k * ITEM + icl[1]];
        float w2 = actW2[(size_t)k * ITEM + icl[2]];
        float w3 = actW2[(size_t)k * ITEM + icl[3]];
        const float* hp = &hT[k * 33 + r0];
#pragma unroll
        for (int r = 0; r < 8; ++r) {
            float hv = hp[r];
            acc[r][0] = fmaf(hv, w0, acc[r][0]);
            acc[r][1] = fmaf(hv, w1, acc[r][1]);
            acc[r][2] = fmaf(hv, w2, acc[r][2]);
            acc[r][3] = fmaf(hv, w3, acc[r][3]);
        }
    }
#pragma unroll
    for (int c = 0; c < 4; ++c) {
        if (icol[c] < ITEM) {
#pragma unroll
            for (int r = 0; r < 8; ++r)
                out[(size_t)(b0 + r0 + r) * ITEM + icol[c]] = acc[r][c];
        }
    }
}

// ---------------- value heads ----------------
__global__ __launch_bounds__(256) void valsker(const float* __restrict__ hid, const float* __restrict__ vW2,
                                               const float* __restrict__ vB2, float* __restrict__ out) {
    int idx = blockIdx.x * 4 + (threadIdx.x >> 6);
    int lane = threadIdx.x & 63;
    if (idx >= 3 * BB) return;
    int k = idx / BB, b = idx - k * BB;
    const float* vh = hid + ((size_t)(k + 1) * BB + b) * LAT;
    float4 a = ((const float4*)vh)[lane];
    float4 w = ((const float4*)(vW2 + k * LAT))[lane];
    float s = a.x * w.x + a.y * w.y + a.z * w.z + a.w * w.w;
#pragma unroll
    for (int o = 32; o; o >>= 1) s += __shfl_down(s, o, 64);
    if (lane == 0) out[(size_t)BB * ITEM + k * BB + b] = s + vB2[k];
}

extern "C" void kernel_launch(void* const* d_in, const int* in_sizes, int n_in,
                              void* d_out, int out_size, void* d_ws, size_t ws_size,
                              hipStream_t stream) {
    const int*   p_rec      = (const int*)d_in[0];
    const int*   p_target   = (const int*)d_in[1];
    const int*   a_rec      = (const int*)d_in[2];
    const float* kn_rec     = (const float*)d_in[3];
    const float* kn_num     = (const float*)d_in[4];
    const int*   src1       = (const int*)d_in[5];
    const int*   dst1       = (const int*)d_in[6];
    const int*   src2       = (const int*)d_in[7];
    const int*   dst2       = (const int*)d_in[8];
    const int*   src3       = (const int*)d_in[9];
    const int*   dst3       = (const int*)d_in[10];
    const float* kn_table   = (const float*)d_in[11];
    const float* exer_table = (const float*)d_in[12];
    const float* ans_table  = (const float*)d_in[13];
    const float* gW         = (const float*)d_in[14];
    const float* gA         = (const float*)d_in[15];
    const float* raW1       = (const float*)d_in[16];
    const float* raB1       = (const float*)d_in[17];
    const float* raW2       = (const float*)d_in[18];
    const float* actW1      = (const float*)d_in[19];
    const float* actB1      = (const float*)d_in[20];
    const float* actW2      = (const float*)d_in[21];
    const float* actB2      = (const float*)d_in[22];
    const float* vW1        = (const float*)d_in[23];
    const float* vB1        = (const float*)d_in[24];
    const float* vW2        = (const float*)d_in[25];
    const float* vB2        = (const float*)d_in[26];
    const int E1 = in_sizes[5], E2 = in_sizes[7];

    float* base = (float*)d_ws;
    size_t o = 0;
    auto alloc = [&](size_t n) -> float* { float* p = base + o; o += (n + 3) & ~(size_t)3; return p; };
    float* buf  = alloc((size_t)NTOT * D);
    float* z1   = alloc((size_t)KNOW * D);
    float* z2   = alloc((size_t)NTOT * D);
    float* z3   = alloc((size_t)NTOT * D);
    float* ds1 = alloc(KNOW);  float* dd1 = alloc(KNOW);
    float* ds2 = alloc(NTOT);  float* dd2 = alloc(NTOT);
    float* ds3 = alloc(NTOT);  float* dd3 = alloc(NTOT);
    int* cnts = (int*)alloc(2 * KNOW + NTOT);
    int* cnt1 = cnts, *cnt2 = cnts + KNOW, *cnt3 = cnts + 2 * KNOW;
    int* off1 = (int*)alloc(KNOW + 1);
    int* off2 = (int*)alloc(KNOW + 1);
    int* off3 = (int*)alloc(ITEM + 1);
    int* es1  = (int*)alloc(E1);
    int* es2  = (int*)alloc(E2);
    int* es3  = (int*)alloc(E2);
    float* krowP = alloc((size_t)CH * BB * KNOW);
    float* hbuf  = alloc((size_t)BB * H3);
    float* hid   = alloc((size_t)4 * BB * LAT);

    hipMemsetAsync(cnts, 0, sizeof(int) * (2 * KNOW + NTOT), stream);

    int etot = E1 + 2 * E2;
    hist3<<<(etot + 255) / 256, 256, 0, stream>>>(dst1, dst2, dst3, E1, E2, cnt1, cnt2, cnt3);
    exscan3<<<3, 1024, 0, stream>>>(cnt1, off1, cnt2, off2, cnt3, off3);
    scatter3<<<(etot + 255) / 256, 256, 0, stream>>>(src1, dst1, src2, dst2, src3, dst3,
                                                     E1, E2, cnt1, cnt2, cnt3, es1, es2, es3);

    // cooperative layer pipeline; fall back to separate launches if the coop launch is rejected
    const float* Xe0 = exer_table;
    const float* Xk0 = kn_table;
    void* args[] = {
        (void*)&Xe0, (void*)&Xk0, (void*)&gW, (void*)&gA,
        (void*)&buf, (void*)&z1, (void*)&z2, (void*)&z3,
        (void*)&ds1, (void*)&dd1, (void*)&ds2, (void*)&dd2, (void*)&ds3, (void*)&dd3,
        (void*)&off1, (void*)&es1, (void*)&off2, (void*)&es2, (void*)&off3, (void*)&es3,
        (void*)&raW1, (void*)&raB1, (void*)&raW2,
        (void*)&kn_rec, (void*)&kn_num, (void*)&p_target, (void*)&krowP
    };
    hipError_t ce = hipLaunchCooperativeKernel((void*)megaker, dim3(MGRID), dim3(256), args, 0, stream);
    if (ce != hipSuccess) {
        for (int l = 0; l < LAYERS; ++l) {
            const float* Xe = (l == 0) ? exer_table : buf;
            const float* Xk = (l == 0) ? kn_table : (buf + (size_t)ITEM * D);
            zdv_ker<<<NZT, 256, 0, stream>>>(Xe, Xk, gW, gA, l, z1, z2, z3,
                                             ds1, dd1, ds2, dd2, ds3, dd3);
            agg3c_ker<<<NAGGU, 256, 0, stream>>>(z1, z2, z3, ds1, dd1, ds2, dd2, ds3, dd3,
                                                 off1, es1, off2, es2, off3, es3,
                                                 raW1 + (size_t)l * D * D, raB1 + (size_t)l * D,
                                                 raW2 + (size_t)l * D, buf);
        }
        krowk_ker<<<dim3(BB, CH), 256, 0, stream>>>(kn_rec, kn_num, p_target, krowP);
    }

    hker<<<BB, 512, 0, stream>>>(buf, ans_table, p_rec, a_rec, p_target, krowP, buf + (size_t)ITEM * D, hbuf);
    hidden_gemm<<<dim3(16, 16), 256, 0, stream>>>(hbuf, actW1, actB1, vW1, vB1, hid);
    logitsker<<<dim3((ITEM + 255) / 256, 8), 256, 0, stream>>>(hid, actW2, actB2, (float*)d_out);
    valsker<<<(3 * BB + 3) / 4, 256, 0, stream>>>(hid, vW2, vB2, (float*)d_out);
}

// Round 16
// 696.096 us; speedup vs baseline: 1.0043x; 1.0043x over previous
//
#include <hip/hip_runtime.h>
#include <hip/hip_cooperative_groups.h>

namespace cg = cooperative_groups;

#define D 128
#define KNOW 1024
#define ITEM 20000
#define NTOT (ITEM + KNOW)
#define LAYERS 2
#define LAT 256
#define BB 256
#define SS 200
#define H3 (3 * D)
#define CH 8
#define ZROWS 64
#define NBK (KNOW / ZROWS)                 // 16
#define NBN ((NTOT + ZROWS - 1) / ZROWS)   // 329
#define NZT (NBK + 2 * NBN)                // 674 zdv tiles
#define NAGGU (KNOW / 4 + ITEM / 4)        // 5256 agg units
#define NKROW (BB * CH)                    // 2048 krowk units
#define XPITCH 68
#define MGRID 256

// ---------------- zdv tile (device fn): z = X@W + dvec for one 64-row tile ----------------
__device__ __forceinline__ void zdv_tile(int bid, int layer, float* __restrict__ xT,
    const float* __restrict__ Xe, const float* __restrict__ Xk,
    const float* __restrict__ gW, const float* __restrict__ gA,
    float* __restrict__ z1, float* __restrict__ z2, float* __restrict__ z3,
    float* __restrict__ ds1, float* __restrict__ dd1,
    float* __restrict__ ds2, float* __restrict__ dd2,
    float* __restrict__ ds3, float* __restrict__ dd3)
{
    int g, row0, nmax;
    if (bid < NBK)            { g = 0; row0 = bid * ZROWS;                nmax = KNOW; }
    else if (bid < NBK + NBN) { g = 1; row0 = (bid - NBK) * ZROWS;        nmax = NTOT; }
    else                      { g = 2; row0 = (bid - NBK - NBN) * ZROWS;  nmax = NTOT; }
    const float* W = gW + (size_t)(layer * 3 + g) * D * D;
    const float* A = gA + (size_t)(layer * 3 + g) * 2 * D;
    float* Z  = (g == 0) ? z1  : (g == 1 ? z2  : z3);
    float* DS = (g == 0) ? ds1 : (g == 1 ? ds2 : ds3);
    float* DD = (g == 0) ? dd1 : (g == 1 ? dd2 : dd3);

    int tid = threadIdx.x;
    __syncthreads();   // previous tile's readers done before overwriting xT
#pragma unroll
    for (int i = 0; i < 8; ++i) {
        int flat = tid + i * 256;
        int row  = flat >> 5;
        int f4   = flat & 31;
        int grow = row0 + row;
        float4 v = make_float4(0.f, 0.f, 0.f, 0.f);
        if (grow < nmax) {
            const float* src = (g == 0) ? (Xk + (size_t)grow * D)
                             : (grow < ITEM ? Xe + (size_t)grow * D
                                            : Xk + (size_t)(grow - ITEM) * D);
            v = *(const float4*)(src + f4 * 4);
        }
        int slot = row ^ ((f4 & 7) << 2);
        int kk = f4 * 4;
        xT[(kk + 0) * XPITCH + slot] = v.x;
        xT[(kk + 1) * XPITCH + slot] = v.y;
        xT[(kk + 2) * XPITCH + slot] = v.z;
        xT[(kk + 3) * XPITCH + slot] = v.w;
    }
    __syncthreads();

    int cg_ = tid & 31;
    int rg = tid >> 5;
    int c0 = cg_ * 4;
    int r0a = rg * 8, r0b = rg * 8 + 4;

    float acc[8][4];
#pragma unroll
    for (int r = 0; r < 8; ++r)
#pragma unroll
        for (int c = 0; c < 4; ++c) acc[r][c] = 0.f;

#pragma unroll 4
    for (int k = 0; k < D; ++k) {
        float4 wv = *(const float4*)(W + (size_t)k * D + c0);
        int xc = ((k >> 2) & 7) << 2;
        float4 xa = *(const float4*)&xT[k * XPITCH + (r0a ^ xc)];
        float4 xb = *(const float4*)&xT[k * XPITCH + (r0b ^ xc)];
        acc[0][0] = fmaf(xa.x, wv.x, acc[0][0]); acc[0][1] = fmaf(xa.x, wv.y, acc[0][1]);
        acc[0][2] = fmaf(xa.x, wv.z, acc[0][2]); acc[0][3] = fmaf(xa.x, wv.w, acc[0][3]);
        acc[1][0] = fmaf(xa.y, wv.x, acc[1][0]); acc[1][1] = fmaf(xa.y, wv.y, acc[1][1]);
        acc[1][2] = fmaf(xa.y, wv.z, acc[1][2]); acc[1][3] = fmaf(xa.y, wv.w, acc[1][3]);
        acc[2][0] = fmaf(xa.z, wv.x, acc[2][0]); acc[2][1] = fmaf(xa.z, wv.y, acc[2][1]);
        acc[2][2] = fmaf(xa.z, wv.z, acc[2][2]); acc[2][3] = fmaf(xa.z, wv.w, acc[2][3]);
        acc[3][0] = fmaf(xa.w, wv.x, acc[3][0]); acc[3][1] = fmaf(xa.w, wv.y, acc[3][1]);
        acc[3][2] = fmaf(xa.w, wv.z, acc[3][2]); acc[3][3] = fmaf(xa.w, wv.w, acc[3][3]);
        acc[4][0] = fmaf(xb.x, wv.x, acc[4][0]); acc[4][1] = fmaf(xb.x, wv.y, acc[4][1]);
        acc[4][2] = fmaf(xb.x, wv.z, acc[4][2]); acc[4][3] = fmaf(xb.x, wv.w, acc[4][3]);
        acc[5][0] = fmaf(xb.y, wv.x, acc[5][0]); acc[5][1] = fmaf(xb.y, wv.y, acc[5][1]);
        acc[5][2] = fmaf(xb.y, wv.z, acc[5][2]); acc[5][3] = fmaf(xb.y, wv.w, acc[5][3]);
        acc[6][0] = fmaf(xb.z, wv.x, acc[6][0]); acc[6][1] = fmaf(xb.z, wv.y, acc[6][1]);
        acc[6][2] = fmaf(xb.z, wv.z, acc[6][2]); acc[6][3] = fmaf(xb.z, wv.w, acc[6][3]);
        acc[7][0] = fmaf(xb.w, wv.x, acc[7][0]); acc[7][1] = fmaf(xb.w, wv.y, acc[7][1]);
        acc[7][2] = fmaf(xb.w, wv.z, acc[7][2]); acc[7][3] = fmaf(xb.w, wv.w, acc[7][3]);
    }

#pragma unroll
    for (int r = 0; r < 8; ++r) {
        int grow = row0 + ((r < 4) ? (r0a + r) : (r0b + r - 4));
        if (grow < nmax) {
            float4 v = make_float4(acc[r][0], acc[r][1], acc[r][2], acc[r][3]);
            *(float4*)(Z + (size_t)grow * D + c0) = v;
        }
    }

    float4 as = *(const float4*)(A + c0);
    float4 ad = *(const float4*)(A + D + c0);
    float ps[8], pd[8];
#pragma unroll
    for (int r = 0; r < 8; ++r) {
        ps[r] = acc[r][0] * as.x + acc[r][1] * as.y + acc[r][2] * as.z + acc[r][3] * as.w;
        pd[r] = acc[r][0] * ad.x + acc[r][1] * ad.y + acc[r][2] * ad.z + acc[r][3] * ad.w;
    }
#pragma unroll
    for (int m = 16; m; m >>= 1) {
#pragma unroll
        for (int r = 0; r < 8; ++r) {
            ps[r] += __shfl_xor(ps[r], m, 64);
            pd[r] += __shfl_xor(pd[r], m, 64);
        }
    }
    if (cg_ == 0) {
#pragma unroll
        for (int r = 0; r < 8; ++r) {
            int grow = row0 + ((r < 4) ? (r0a + r) : (r0b + r - 4));
            if (grow < nmax) { DS[grow] = ps[r]; DD[grow] = pd[r]; }
        }
    }
}

// ---------------- per-row attention aggregation, 4-way edge-parallel ----------------
__device__ __forceinline__ void agg_row(const float* __restrict__ Z, const float* __restrict__ dsrc,
                                        float dd, const int* __restrict__ es, int e0, int e1,
                                        int lane, float* __restrict__ acc) {
#pragma unroll
    for (int q = 0; q < 8; ++q) acc[q] = 0.f;
    if (e1 <= e0) return;
    float mx = -3.4e38f;
    for (int e = e0 + lane; e < e1; e += 64) {
        float t = dsrc[es[e]] + dd;
        t = (t > 0.f) ? t : 0.01f * t;
        mx = fmaxf(mx, t);
    }
#pragma unroll
    for (int o = 32; o; o >>= 1) mx = fmaxf(mx, __shfl_xor(mx, o, 64));
    int eg = lane >> 4, cs = lane & 15;
    float den = 0.f;
    for (int e = e0 + eg; e < e1; e += 4) {
        int s = es[e];
        float t = dsrc[s] + dd;
        t = (t > 0.f) ? t : 0.01f * t;
        float w = __expf(t - mx);
        den += w;
        const float4* zr = (const float4*)(Z + (size_t)s * D + cs * 8);
        float4 za = zr[0], zb = zr[1];
        acc[0] = fmaf(w, za.x, acc[0]); acc[1] = fmaf(w, za.y, acc[1]);
        acc[2] = fmaf(w, za.z, acc[2]); acc[3] = fmaf(w, za.w, acc[3]);
        acc[4] = fmaf(w, zb.x, acc[4]); acc[5] = fmaf(w, zb.y, acc[5]);
        acc[6] = fmaf(w, zb.z, acc[6]); acc[7] = fmaf(w, zb.w, acc[7]);
    }
#pragma unroll
    for (int m = 16; m <= 32; m <<= 1) {
        den += __shfl_xor(den, m, 64);
#pragma unroll
        for (int q = 0; q < 8; ++q) acc[q] += __shfl_xor(acc[q], m, 64);
    }
    float inv = 1.f / fmaxf(den, 1e-12f);
#pragma unroll
    for (int q = 0; q < 8; ++q) acc[q] *= inv;
}

// ---------------- agg unit (device fn): paired kdir/kfe + combine, or graph3 row ----------------
__device__ __forceinline__ void agg_unit(int u, float (*ABs)[2][D],
    const float* __restrict__ z1, const float* __restrict__ z2, const float* __restrict__ z3,
    const float* __restrict__ ds1, const float* __restrict__ dd1,
    const float* __restrict__ ds2, const float* __restrict__ dd2,
    const float* __restrict__ ds3, const float* __restrict__ dd3,
    const int* __restrict__ off1, const int* __restrict__ es1,
    const int* __restrict__ off2, const int* __restrict__ es2,
    const int* __restrict__ off3, const int* __restrict__ es3,
    const float* __restrict__ raW1L, const float* __restrict__ raB1L,
    const float* __restrict__ raW2L, float* __restrict__ buf)
{
    int wv = threadIdx.x >> 6, lane = threadIdx.x & 63;
    int eg = lane >> 4, cs = lane & 15;
    if (u < KNOW / 4) {
        __syncthreads();   // ABs reuse guard
        int i = u * 4 + wv;
        float accA[8], accB[8];
        agg_row(z1, ds1, dd1[i], es1, off1[i], off1[i + 1], lane, accA);
        agg_row(z2, ds2, dd2[ITEM + i], es2, off2[i], off2[i + 1], lane, accB);
        if (eg == 0) {
            *(float4*)&ABs[wv][0][cs * 8]     = make_float4(accA[0], accA[1], accA[2], accA[3]);
            *(float4*)&ABs[wv][0][cs * 8 + 4] = make_float4(accA[4], accA[5], accA[6], accA[7]);
            *(float4*)&ABs[wv][1][cs * 8]     = make_float4(accB[0], accB[1], accB[2], accB[3]);
            *(float4*)&ABs[wv][1][cs * 8 + 4] = make_float4(accB[4], accB[5], accB[6], accB[7]);
        }
        __syncthreads();
        int j0 = lane * 2;
        float b0 = raB1L[j0], b1 = raB1L[j0 + 1];
        float aA0 = b0, aA1 = b1, aB0 = b0, aB1 = b1;
#pragma unroll 4
        for (int k = 0; k < D; ++k) {
            float av = ABs[wv][0][k], bv = ABs[wv][1][k];
            float2 w = *(const float2*)(raW1L + (size_t)k * D + j0);
            aA0 = fmaf(av, w.x, aA0); aA1 = fmaf(av, w.y, aA1);
            aB0 = fmaf(bv, w.x, aB0); aB1 = fmaf(bv, w.y, aB1);
        }
        float2 w2 = *(const float2*)(raW2L + j0);
        float pA = tanhf(aA0) * w2.x + tanhf(aA1) * w2.y;
        float pB = tanhf(aB0) * w2.x + tanhf(aB1) * w2.y;
#pragma unroll
        for (int o = 32; o; o >>= 1) { pA += __shfl_xor(pA, o, 64); pB += __shfl_xor(pB, o, 64); }
        float mx2 = fmaxf(pA, pB);
        float eA = __expf(pA - mx2), eB = __expf(pB - mx2);
        float s = 1.f / (eA + eB);
        float sA = eA * s, sB = eB * s;
        float2 Av = *(float2*)&ABs[wv][0][j0];
        float2 Bv = *(float2*)&ABs[wv][1][j0];
        *(float2*)(buf + (size_t)(ITEM + i) * D + j0) =
            make_float2(sA * Av.x + sB * Bv.x, sA * Av.y + sB * Bv.y);
    } else {
        int row = (u - KNOW / 4) * 4 + wv;
        if (row < ITEM) {
            float acc[8];
            agg_row(z3, ds3, dd3[row], es3, off3[row], off3[row + 1], lane, acc);
            if (eg == 0) {
                *(float4*)(buf + (size_t)row * D + cs * 8)     = make_float4(acc[0], acc[1], acc[2], acc[3]);
                *(float4*)(buf + (size_t)row * D + cs * 8 + 4) = make_float4(acc[4], acc[5], acc[6], acc[7]);
            }
        }
    }
}

// ---------------- krowk unit (device fn) ----------------
__device__ __forceinline__ void krow_unit(int uk, const float* __restrict__ kn_rec,
                                          const float* __restrict__ kn_num,
                                          const int* __restrict__ p_target, float* __restrict__ krowP)
{
    int b = uk & (BB - 1), ch = uk >> 8;
    int cnt = p_target[b] + 1;
    int per = (SS + CH - 1) / CH;
    int s0 = ch * per, s1 = s0 + per;
    if (s1 > cnt) s1 = cnt;
    int k0 = threadIdx.x * 4;
    float4 a = make_float4(0.f, 0.f, 0.f, 0.f);
    for (int s = s0; s < s1; ++s) {
        float inv = 1.f / kn_num[b * SS + s];
        float4 v = *(const float4*)(kn_rec + ((size_t)b * SS + s) * KNOW + k0);
        a.x += v.x * inv; a.y += v.y * inv; a.z += v.z * inv; a.w += v.w * inv;
    }
    *(float4*)(krowP + ((size_t)ch * BB + b) * KNOW + k0) = a;
}

// ---------------- cooperative mega-kernel: [zdv -> agg(+krowk)] x 2 layers ----------------
__global__ __launch_bounds__(256) void megaker(
    const float* Xe0, const float* Xk0, const float* gW, const float* gA,
    float* buf, float* z1, float* z2, float* z3,
    float* ds1, float* dd1, float* ds2, float* dd2, float* ds3, float* dd3,
    const int* off1, const int* es1, const int* off2, const int* es2,
    const int* off3, const int* es3,
    const float* raW1, const float* raB1, const float* raW2,
    const float* kn_rec, const float* kn_num, const int* p_target, float* krowP)
{
    cg::grid_group grid = cg::this_grid();
    __shared__ __align__(16) float xT[D * XPITCH];     // 34.8 KB
    __shared__ float ABs[4][2][D];                      // 4 KB
    for (int l = 0; l < LAYERS; ++l) {
        const float* Xe = (l == 0) ? Xe0 : buf;
        const float* Xk = (l == 0) ? Xk0 : (buf + (size_t)ITEM * D);
        for (int t = blockIdx.x; t < NZT; t += MGRID)
            zdv_tile(t, l, xT, Xe, Xk, gW, gA, z1, z2, z3, ds1, dd1, ds2, dd2, ds3, dd3);
        grid.sync();
        int nu = NAGGU + ((l == 0) ? NKROW : 0);
        for (int u = blockIdx.x; u < nu; u += MGRID) {
            if (u < NAGGU)
                agg_unit(u, ABs, z1, z2, z3, ds1, dd1, ds2, dd2, ds3, dd3,
                         off1, es1, off2, es2, off3, es3,
                         raW1 + (size_t)l * D * D, raB1 + (size_t)l * D, raW2 + (size_t)l * D, buf);
            else
                krow_unit(u - NAGGU, kn_rec, kn_num, p_target, krowP);
        }
        grid.sync();
    }
}

// ---------------- fallback wrappers (separate launches, known-good R13 path) ----------------
__global__ __launch_bounds__(256) void zdv_ker(
    const float* __restrict__ Xe, const float* __restrict__ Xk,
    const float* __restrict__ gW, const float* __restrict__ gA, int layer,
    float* __restrict__ z1, float* __restrict__ z2, float* __restrict__ z3,
    float* __restrict__ ds1, float* __restrict__ dd1,
    float* __restrict__ ds2, float* __restrict__ dd2,
    float* __restrict__ ds3, float* __restrict__ dd3)
{
    __shared__ __align__(16) float xT[D * XPITCH];
    zdv_tile(blockIdx.x, layer, xT, Xe, Xk, gW, gA, z1, z2, z3, ds1, dd1, ds2, dd2, ds3, dd3);
}

__global__ __launch_bounds__(256) void agg3c_ker(
    const float* __restrict__ z1, const float* __restrict__ z2, const float* __restrict__ z3,
    const float* __restrict__ ds1, const float* __restrict__ dd1,
    const float* __restrict__ ds2, const float* __restrict__ dd2,
    const float* __restrict__ ds3, const float* __restrict__ dd3,
    const int* __restrict__ off1, const int* __restrict__ es1,
    const int* __restrict__ off2, const int* __restrict__ es2,
    const int* __restrict__ off3, const int* __restrict__ es3,
    const float* __restrict__ raW1L, const float* __restrict__ raB1L,
    const float* __restrict__ raW2L, float* __restrict__ buf)
{
    __shared__ float ABs[4][2][D];
    agg_unit(blockIdx.x, ABs, z1, z2, z3, ds1, dd1, ds2, dd2, ds3, dd3,
             off1, es1, off2, es2, off3, es3, raW1L, raB1L, raW2L, buf);
}

__global__ __launch_bounds__(256) void krowk_ker(const float* __restrict__ kn_rec,
                                                 const float* __restrict__ kn_num,
                                                 const int* __restrict__ p_target,
                                                 float* __restrict__ krowP) {
    krow_unit(blockIdx.y * BB + blockIdx.x, kn_rec, kn_num, p_target, krowP);
}

// ---------------- CSR build ----------------
__global__ void hist3(const int* __restrict__ d1, const int* __restrict__ d2, const int* __restrict__ d3,
                      int E1, int E2, int* __restrict__ c1, int* __restrict__ c2, int* __restrict__ c3) {
    int i = blockIdx.x * blockDim.x + threadIdx.x;
    if (i < E1) atomicAdd(&c1[d1[i]], 1);
    else if (i < E1 + E2) { int d = d2[i - E1]; if (d >= ITEM) atomicAdd(&c2[d - ITEM], 1); }
    else if (i < E1 + 2 * E2) { int d = d3[i - E1 - E2]; if (d < ITEM) atomicAdd(&c3[d], 1); }
}

__global__ __launch_bounds__(1024) void exscan3(int* __restrict__ c1, int* __restrict__ o1,
                                                int* __restrict__ c2, int* __restrict__ o2,
                                                int* __restrict__ c3, int* __restrict__ o3) {
    int g = blockIdx.x;
    int* cnt = (g == 0) ? c1 : (g == 1 ? c2 : c3);
    int* off = (g == 0) ? o1 : (g == 1 ? o2 : o3);
    int n = (g == 2) ? ITEM : KNOW;
    int tid = threadIdx.x, lane = tid & 63, wid = tid >> 6;
    int L = (n + 1023) >> 10;
    int i0 = tid * L;
    int sum = 0;
    for (int q = 0; q < L; ++q) {
        int i = i0 + q;
        if (i < n) sum += cnt[i];
    }
    int x = sum;
#pragma unroll
    for (int d = 1; d < 64; d <<= 1) { int t = __shfl_up(x, d, 64); if (lane >= d) x += t; }
    __shared__ int ws[16];
    if (lane == 63) ws[wid] = x;
    __syncthreads();
    if (wid == 0) {
        int w = (lane < 16) ? ws[lane] : 0;
#pragma unroll
        for (int d = 1; d < 16; d <<= 1) { int t = __shfl_up(w, d, 64); if (lane >= d) w += t; }
        if (lane < 16) ws[lane] = w;
    }
    __syncthreads();
    int run = x - sum + ((wid > 0) ? ws[wid - 1] : 0);
    if (tid == 0) off[0] = 0;
    for (int q = 0; q < L; ++q) {
        int i = i0 + q;
        if (i < n) {
            int v = cnt[i];
            cnt[i] = run;
            run += v;
            off[i + 1] = run;
        }
    }
}

__global__ void scatter3(const int* __restrict__ s1, const int* __restrict__ d1,
                         const int* __restrict__ s2, const int* __restrict__ d2,
                         const int* __restrict__ s3, const int* __restrict__ d3,
                         int E1, int E2, int* __restrict__ cur1, int* __restrict__ cur2, int* __restrict__ cur3,
                         int* __restrict__ e1, int* __restrict__ e2, int* __restrict__ e3) {
    int i = blockIdx.x * blockDim.x + threadIdx.x;
    if (i < E1) { int p = atomicAdd(&cur1[d1[i]], 1); e1[p] = s1[i]; }
    else if (i < E1 + E2) { int j = i - E1; int d = d2[j]; if (d >= ITEM) { int p = atomicAdd(&cur2[d - ITEM], 1); e2[p] = s2[j]; } }
    else if (i < E1 + 2 * E2) { int j = i - E1 - E2; int d = d3[j]; if (d < ITEM) { int p = atomicAdd(&cur3[d], 1); e3[p] = s3[j]; } }
}

// ---------------- h assembly ----------------
__global__ __launch_bounds__(512) void hker(const float* __restrict__ ex, const float* __restrict__ ans_table,
                                            const int* __restrict__ p_rec, const int* __restrict__ a_rec,
                                            const int* __restrict__ p_target, const float* __restrict__ krowP,
                                            const float* __restrict__ kn, float* __restrict__ h) {
    int b = blockIdx.x;
    int j = threadIdx.x & 127, sg = threadIdx.x >> 7;
    int cnt = p_target[b] + 1;
    __shared__ int pidx[SS], aidx[SS];
    __shared__ float kr[KNOW];
    __shared__ float red[4][3][128];
    for (int i = threadIdx.x; i < cnt; i += 512) { pidx[i] = p_rec[b * SS + i]; aidx[i] = a_rec[b * SS + i]; }
    for (int i = threadIdx.x; i < KNOW; i += 512) {
        float s = 0.f;
#pragma unroll
        for (int c = 0; c < CH; ++c) s += krowP[((size_t)c * BB + b) * KNOW + i];
        kr[i] = s;
    }
    __syncthreads();
    float accE = 0.f, accA = 0.f;
    for (int s = sg; s < cnt; s += 4) {
        accE += ex[(size_t)pidx[s] * D + j];
        accA += ans_table[aidx[s] * D + j];
    }
    float accK = 0.f;
    for (int k = sg * 256; k < sg * 256 + 256; ++k) accK += kr[k] * kn[(size_t)k * D + j];
    red[sg][0][j] = accE; red[sg][1][j] = accA; red[sg][2][j] = accK;
    __syncthreads();
    if (sg == 0) {
        float inv = 1.f / (float)cnt;
        float e = (red[0][0][j] + red[1][0][j] + red[2][0][j] + red[3][0][j]) * inv;
        float a = (red[0][1][j] + red[1][1][j] + red[2][1][j] + red[3][1][j]) * inv;
        float kv = (red[0][2][j] + red[1][2][j] + red[2][2][j] + red[3][2][j]) * inv;
        h[b * H3 + j] = e;
        h[b * H3 + D + j] = a;
        h[b * H3 + 2 * D + j] = kv;
    }
}

// ---------------- unified hidden GEMM ----------------
__global__ __launch_bounds__(256) void hidden_gemm(const float* __restrict__ h,
                                                   const float* __restrict__ actW1, const float* __restrict__ actB1,
                                                   const float* __restrict__ vW1, const float* __restrict__ vB1,
                                                   float* __restrict__ hid) {
    __shared__ float hT[H3 * 17];
    int tid = threadIdx.x;
    int b0 = blockIdx.y * 16;
    for (int idx = tid; idx < 16 * H3; idx += 256) {
        int r = idx / H3, k = idx - r * H3;
        hT[k * 17 + r] = h[(size_t)(b0 + r) * H3 + k];
    }
    __syncthreads();
    int j = blockIdx.x * 64 + (tid & 63);
    int head = j >> 8, jj = j & 255;
    int rg = tid >> 6, r0 = rg * 4;
    const float* W = (head == 0) ? actW1 : (vW1 + (size_t)(head - 1) * H3 * LAT);
    float bias = (head == 0) ? actB1[jj] : vB1[(head - 1) * LAT + jj];
    float acc[4] = {bias, bias, bias, bias};
#pragma unroll 4
    for (int k = 0; k < H3; ++k) {
        float w = W[(size_t)k * LAT + jj];
        float h0 = hT[k * 17 + r0 + 0];
        float h1 = hT[k * 17 + r0 + 1];
        float h2 = hT[k * 17 + r0 + 2];
        float h3 = hT[k * 17 + r0 + 3];
        acc[0] = fmaf(h0, w, acc[0]);
        acc[1] = fmaf(h1, w, acc[1]);
        acc[2] = fmaf(h2, w, acc[2]);
        acc[3] = fmaf(h3, w, acc[3]);
    }
#pragma unroll
    for (int r = 0; r < 4; ++r)
        hid[((size_t)head * BB + (b0 + r0 + r)) * LAT + jj] = tanhf(acc[r]);
}

// ---------------- logits GEMM ----------------
__global__ __launch_bounds__(256) void logitsker(const float* __restrict__ hid, const float* __restrict__ actW2,
                                                 const float* __restrict__ actB2, float* __restrict__ out) {
    __shared__ float hT[LAT * 33];
    int tid = threadIdx.x;
    int b0 = blockIdx.y * 32;
    for (int idx = tid; idx < 32 * LAT; idx += 256) {
        int r = idx >> 8, k = idx & 255;
        hT[k * 33 + r] = hid[(size_t)(b0 + r) * LAT + k];
    }
    __syncthreads();
    int lane6 = tid & 63;
    int rg = tid >> 6, r0 = rg * 8;
    int ibase = blockIdx.x * 256 + lane6;
    int icol[4], icl[4];
    float bias[4];
#pragma unroll
    for (int c = 0; c < 4; ++c) {
        icol[c] = ibase + c * 64;
        icl[c] = icol[c] < ITEM ? icol[c] : (ITEM - 1);
        bias[c] = actB2[icl[c]];
    }
    float acc[8][4];
#pragma unroll
    for (int r = 0; r < 8; ++r)
#pragma unroll
        for (int c = 0; c < 4; ++c) acc[r][c] = bias[c];
#pragma unroll 2
    for (int k = 0; k < LAT; ++k) {
        float w0 = actW2[(size_t)k * ITEM + icl[0]];
        float w1 = actW2[(size_t)k * ITEM + icl[1]];
        float w2 = actW2[(size_t)k * ITEM + icl[2]];
        float w3 = actW2[(size_t)k * ITEM + icl[3]];
        const float* hp = &hT[k * 33 + r0];
#pragma unroll
        for (int r = 0; r < 8; ++r) {
            float hv = hp[r];
            acc[r][0] = fmaf(hv, w0, acc[r][0]);
            acc[r][1] = fmaf(hv, w1, acc[r][1]);
            acc[r][2] = fmaf(hv, w2, acc[r][2]);
            acc[r][3] = fmaf(hv, w3, acc[r][3]);
        }
    }
#pragma unroll
    for (int c = 0; c < 4; ++c) {
        if (icol[c] < ITEM) {
#pragma unroll
            for (int r = 0; r < 8; ++r)
                out[(size_t)(b0 + r0 + r) * ITEM + icol[c]] = acc[r][c];
        }
    }
}

// ---------------- value heads ----------------
__global__ __launch_bounds__(256) void valsker(const float* __restrict__ hid, const float* __restrict__ vW2,
                                               const float* __restrict__ vB2, float* __restrict__ out) {
    int idx = blockIdx.x * 4 + (threadIdx.x >> 6);
    int lane = threadIdx.x & 63;
    if (idx >= 3 * BB) return;
    int k = idx / BB, b = idx - k * BB;
    const float* vh = hid + ((size_t)(k + 1) * BB + b) * LAT;
    float4 a = ((const float4*)vh)[lane];
    float4 w = ((const float4*)(vW2 + k * LAT))[lane];
    float s = a.x * w.x + a.y * w.y + a.z * w.z + a.w * w.w;
#pragma unroll
    for (int o = 32; o; o >>= 1) s += __shfl_down(s, o, 64);
    if (lane == 0) out[(size_t)BB * ITEM + k * BB + b] = s + vB2[k];
}

extern "C" void kernel_launch(void* const* d_in, const int* in_sizes, int n_in,
                              void* d_out, int out_size, void* d_ws, size_t ws_size,
                              hipStream_t stream) {
    const int*   p_rec      = (const int*)d_in[0];
    const int*   p_target   = (const int*)d_in[1];
    const int*   a_rec      = (const int*)d_in[2];
    const float* kn_rec     = (const float*)d_in[3];
    const float* kn_num     = (const float*)d_in[4];
    const int*   src1       = (const int*)d_in[5];
    const int*   dst1       = (const int*)d_in[6];
    const int*   src2       = (const int*)d_in[7];
    const int*   dst2       = (const int*)d_in[8];
    const int*   src3       = (const int*)d_in[9];
    const int*   dst3       = (const int*)d_in[10];
    const float* kn_table   = (const float*)d_in[11];
    const float* exer_table = (const float*)d_in[12];
    const float* ans_table  = (const float*)d_in[13];
    const float* gW         = (const float*)d_in[14];
    const float* gA         = (const float*)d_in[15];
    const float* raW1       = (const float*)d_in[16];
    const float* raB1       = (const float*)d_in[17];
    const float* raW2       = (const float*)d_in[18];
    const float* actW1      = (const float*)d_in[19];
    const float* actB1      = (const float*)d_in[20];
    const float* actW2      = (const float*)d_in[21];
    const float* actB2      = (const float*)d_in[22];
    const float* vW1        = (const float*)d_in[23];
    const float* vB1        = (const float*)d_in[24];
    const float* vW2        = (const float*)d_in[25];
    const float* vB2        = (const float*)d_in[26];
    const int E1 = in_sizes[5], E2 = in_sizes[7];

    float* base = (float*)d_ws;
    size_t o = 0;
    auto alloc = [&](size_t n) -> float* { float* p = base + o; o += (n + 3) & ~(size_t)3; return p; };
    float* buf  = alloc((size_t)NTOT * D);
    float* z1   = alloc((size_t)KNOW * D);
    float* z2   = alloc((size_t)NTOT * D);
    float* z3   = alloc((size_t)NTOT * D);
    float* ds1 = alloc(KNOW);  float* dd1 = alloc(KNOW);
    float* ds2 = alloc(NTOT);  float* dd2 = alloc(NTOT);
    float* ds3 = alloc(NTOT);  float* dd3 = alloc(NTOT);
    int* cnts = (int*)alloc(2 * KNOW + NTOT);
    int* cnt1 = cnts, *cnt2 = cnts + KNOW, *cnt3 = cnts + 2 * KNOW;
    int* off1 = (int*)alloc(KNOW + 1);
    int* off2 = (int*)alloc(KNOW + 1);
    int* off3 = (int*)alloc(ITEM + 1);
    int* es1  = (int*)alloc(E1);
    int* es2  = (int*)alloc(E2);
    int* es3  = (int*)alloc(E2);
    float* krowP = alloc((size_t)CH * BB * KNOW);
    float* hbuf  = alloc((size_t)BB * H3);
    float* hid   = alloc((size_t)4 * BB * LAT);

    hipMemsetAsync(cnts, 0, sizeof(int) * (2 * KNOW + NTOT), stream);

    int etot = E1 + 2 * E2;
    hist3<<<(etot + 255) / 256, 256, 0, stream>>>(dst1, dst2, dst3, E1, E2, cnt1, cnt2, cnt3);
    exscan3<<<3, 1024, 0, stream>>>(cnt1, off1, cnt2, off2, cnt3, off3);
    scatter3<<<(etot + 255) / 256, 256, 0, stream>>>(src1, dst1, src2, dst2, src3, dst3,
                                                     E1, E2, cnt1, cnt2, cnt3, es1, es2, es3);

    // cooperative layer pipeline; fall back to separate launches if the coop launch is rejected
    const float* Xe0 = exer_table;
    const float* Xk0 = kn_table;
    void* args[] = {
        (void*)&Xe0, (void*)&Xk0, (void*)&gW, (void*)&gA,
        (void*)&buf, (void*)&z1, (void*)&z2, (void*)&z3,
        (void*)&ds1, (void*)&dd1, (void*)&ds2, (void*)&dd2, (void*)&ds3, (void*)&dd3,
        (void*)&off1, (void*)&es1, (void*)&off2, (void*)&es2, (void*)&off3, (void*)&es3,
        (void*)&raW1, (void*)&raB1, (void*)&raW2,
        (void*)&kn_rec, (void*)&kn_num, (void*)&p_target, (void*)&krowP
    };
    hipError_t ce = hipLaunchCooperativeKernel((void*)megaker, dim3(MGRID), dim3(256), args, 0, stream);
    if (ce != hipSuccess) {
        for (int l = 0; l < LAYERS; ++l) {
            const float* Xe = (l == 0) ? exer_table : buf;
            const float* Xk = (l == 0) ? kn_table : (buf + (size_t)ITEM * D);
            zdv_ker<<<NZT, 256, 0, stream>>>(Xe, Xk, gW, gA, l, z1, z2, z3,
                                             ds1, dd1, ds2, dd2, ds3, dd3);
            agg3c_ker<<<NAGGU, 256, 0, stream>>>(z1, z2, z3, ds1, dd1, ds2, dd2, ds3, dd3,
                                                 off1, es1, off2, es2, off3, es3,
                                                 raW1 + (size_t)l * D * D, raB1 + (size_t)l * D,
                                                 raW2 + (size_t)l * D, buf);
        }
        krowk_ker<<<dim3(BB, CH), 256, 0, stream>>>(kn_rec, kn_num, p_target, krowP);
    }

    hker<<<BB, 512, 0, stream>>>(buf, ans_table, p_rec, a_rec, p_target, krowP, buf + (size_t)ITEM * D, hbuf);
    hidden_gemm<<<dim3(16, 16), 256, 0, stream>>>(hbuf, actW1, actB1, vW1, vB1, hid);
    logitsker<<<dim3((ITEM + 255) / 256, 8), 256, 0, stream>>>(hid, actW2, actB2, (float*)d_out);
    valsker<<<(3 * BB + 3) / 4, 256, 0, stream>>>(hid, vW2, vB2, (float*)d_out);
}

// Round 17
// 303.515 us; speedup vs baseline: 2.3033x; 2.2934x over previous
//
#include <hip/hip_runtime.h>

#define D 128
#define KNOW 1024
#define ITEM 20000
#define NTOT (ITEM + KNOW)
#define LAYERS 2
#define LAT 256
#define BB 256
#define SS 200
#define H3 (3 * D)
#define CH 4
#define ZROWS 64
#define NBK (KNOW / ZROWS)                 // 16
#define NBN ((NTOT + ZROWS - 1) / ZROWS)   // 329
#define NZT (NBK + 2 * NBN)                // 674 zdv tiles
#define NAGGU (KNOW / 4 + ITEM / 4)        // 5256 agg units
#define NKROW (BB * CH)                    // 1024 krow units
#define XPITCH 68
#define NLOGB ((ITEM + 255) / 256)         // 79
#define NLV (NLOGB * (BB / 32))            // 632 logits blocks
#define NVB ((3 * BB + 3) / 4)             // 192 vals blocks

// ---------------- fused z = X@W plus dvec (dsrc/ddst) for all 3 graphs ----------------
__global__ __launch_bounds__(256) void zdv_ker(
    const float* __restrict__ Xe, const float* __restrict__ Xk,
    const float* __restrict__ gW, const float* __restrict__ gA, int layer,
    float* __restrict__ z1, float* __restrict__ z2, float* __restrict__ z3,
    float* __restrict__ ds1, float* __restrict__ dd1,
    float* __restrict__ ds2, float* __restrict__ dd2,
    float* __restrict__ ds3, float* __restrict__ dd3)
{
    __shared__ __align__(16) float xT[D * XPITCH];   // 34.8 KB
    int bid = blockIdx.x;
    int g, row0, nmax;
    if (bid < NBK)            { g = 0; row0 = bid * ZROWS;                nmax = KNOW; }
    else if (bid < NBK + NBN) { g = 1; row0 = (bid - NBK) * ZROWS;        nmax = NTOT; }
    else                      { g = 2; row0 = (bid - NBK - NBN) * ZROWS;  nmax = NTOT; }
    const float* W = gW + (size_t)(layer * 3 + g) * D * D;
    const float* A = gA + (size_t)(layer * 3 + g) * 2 * D;
    float* Z  = (g == 0) ? z1  : (g == 1 ? z2  : z3);
    float* DS = (g == 0) ? ds1 : (g == 1 ? ds2 : ds3);
    float* DD = (g == 0) ? dd1 : (g == 1 ? dd2 : dd3);

    int tid = threadIdx.x;
#pragma unroll
    for (int i = 0; i < 8; ++i) {
        int flat = tid + i * 256;
        int row  = flat >> 5;
        int f4   = flat & 31;
        int grow = row0 + row;
        float4 v = make_float4(0.f, 0.f, 0.f, 0.f);
        if (grow < nmax) {
            const float* src = (g == 0) ? (Xk + (size_t)grow * D)
                             : (grow < ITEM ? Xe + (size_t)grow * D
                                            : Xk + (size_t)(grow - ITEM) * D);
            v = *(const float4*)(src + f4 * 4);
        }
        int slot = row ^ ((f4 & 7) << 2);
        int kk = f4 * 4;
        xT[(kk + 0) * XPITCH + slot] = v.x;
        xT[(kk + 1) * XPITCH + slot] = v.y;
        xT[(kk + 2) * XPITCH + slot] = v.z;
        xT[(kk + 3) * XPITCH + slot] = v.w;
    }
    __syncthreads();

    int cg_ = tid & 31;
    int rg = tid >> 5;
    int c0 = cg_ * 4;
    int r0a = rg * 8, r0b = rg * 8 + 4;

    float acc[8][4];
#pragma unroll
    for (int r = 0; r < 8; ++r)
#pragma unroll
        for (int c = 0; c < 4; ++c) acc[r][c] = 0.f;

#pragma unroll 4
    for (int k = 0; k < D; ++k) {
        float4 wv = *(const float4*)(W + (size_t)k * D + c0);
        int xc = ((k >> 2) & 7) << 2;
        float4 xa = *(const float4*)&xT[k * XPITCH + (r0a ^ xc)];
        float4 xb = *(const float4*)&xT[k * XPITCH + (r0b ^ xc)];
        acc[0][0] = fmaf(xa.x, wv.x, acc[0][0]); acc[0][1] = fmaf(xa.x, wv.y, acc[0][1]);
        acc[0][2] = fmaf(xa.x, wv.z, acc[0][2]); acc[0][3] = fmaf(xa.x, wv.w, acc[0][3]);
        acc[1][0] = fmaf(xa.y, wv.x, acc[1][0]); acc[1][1] = fmaf(xa.y, wv.y, acc[1][1]);
        acc[1][2] = fmaf(xa.y, wv.z, acc[1][2]); acc[1][3] = fmaf(xa.y, wv.w, acc[1][3]);
        acc[2][0] = fmaf(xa.z, wv.x, acc[2][0]); acc[2][1] = fmaf(xa.z, wv.y, acc[2][1]);
        acc[2][2] = fmaf(xa.z, wv.z, acc[2][2]); acc[2][3] = fmaf(xa.z, wv.w, acc[2][3]);
        acc[3][0] = fmaf(xa.w, wv.x, acc[3][0]); acc[3][1] = fmaf(xa.w, wv.y, acc[3][1]);
        acc[3][2] = fmaf(xa.w, wv.z, acc[3][2]); acc[3][3] = fmaf(xa.w, wv.w, acc[3][3]);
        acc[4][0] = fmaf(xb.x, wv.x, acc[4][0]); acc[4][1] = fmaf(xb.x, wv.y, acc[4][1]);
        acc[4][2] = fmaf(xb.x, wv.z, acc[4][2]); acc[4][3] = fmaf(xb.x, wv.w, acc[4][3]);
        acc[5][0] = fmaf(xb.y, wv.x, acc[5][0]); acc[5][1] = fmaf(xb.y, wv.y, acc[5][1]);
        acc[5][2] = fmaf(xb.y, wv.z, acc[5][2]); acc[5][3] = fmaf(xb.y, wv.w, acc[5][3]);
        acc[6][0] = fmaf(xb.z, wv.x, acc[6][0]); acc[6][1] = fmaf(xb.z, wv.y, acc[6][1]);
        acc[6][2] = fmaf(xb.z, wv.z, acc[6][2]); acc[6][3] = fmaf(xb.z, wv.w, acc[6][3]);
        acc[7][0] = fmaf(xb.w, wv.x, acc[7][0]); acc[7][1] = fmaf(xb.w, wv.y, acc[7][1]);
        acc[7][2] = fmaf(xb.w, wv.z, acc[7][2]); acc[7][3] = fmaf(xb.w, wv.w, acc[7][3]);
    }

#pragma unroll
    for (int r = 0; r < 8; ++r) {
        int grow = row0 + ((r < 4) ? (r0a + r) : (r0b + r - 4));
        if (grow < nmax) {
            float4 v = make_float4(acc[r][0], acc[r][1], acc[r][2], acc[r][3]);
            *(float4*)(Z + (size_t)grow * D + c0) = v;
        }
    }

    float4 as = *(const float4*)(A + c0);
    float4 ad = *(const float4*)(A + D + c0);
    float ps[8], pd[8];
#pragma unroll
    for (int r = 0; r < 8; ++r) {
        ps[r] = acc[r][0] * as.x + acc[r][1] * as.y + acc[r][2] * as.z + acc[r][3] * as.w;
        pd[r] = acc[r][0] * ad.x + acc[r][1] * ad.y + acc[r][2] * ad.z + acc[r][3] * ad.w;
    }
#pragma unroll
    for (int m = 16; m; m >>= 1) {
#pragma unroll
        for (int r = 0; r < 8; ++r) {
            ps[r] += __shfl_xor(ps[r], m, 64);
            pd[r] += __shfl_xor(pd[r], m, 64);
        }
    }
    if (cg_ == 0) {
#pragma unroll
        for (int r = 0; r < 8; ++r) {
            int grow = row0 + ((r < 4) ? (r0a + r) : (r0b + r - 4));
            if (grow < nmax) { DS[grow] = ps[r]; DD[grow] = pd[r]; }
        }
    }
}

// ---------------- CSR build (graph2: dst >= ITEM; graph3: dst < ITEM) ----------------
__global__ void hist3(const int* __restrict__ d1, const int* __restrict__ d2, const int* __restrict__ d3,
                      int E1, int E2, int* __restrict__ c1, int* __restrict__ c2, int* __restrict__ c3) {
    int i = blockIdx.x * blockDim.x + threadIdx.x;
    if (i < E1) atomicAdd(&c1[d1[i]], 1);
    else if (i < E1 + E2) { int d = d2[i - E1]; if (d >= ITEM) atomicAdd(&c2[d - ITEM], 1); }
    else if (i < E1 + 2 * E2) { int d = d3[i - E1 - E2]; if (d < ITEM) atomicAdd(&c3[d], 1); }
}

// Thread-chunked exclusive scan: 2 barriers total.
__global__ __launch_bounds__(1024) void exscan3(int* __restrict__ c1, int* __restrict__ o1,
                                                int* __restrict__ c2, int* __restrict__ o2,
                                                int* __restrict__ c3, int* __restrict__ o3) {
    int g = blockIdx.x;
    int* cnt = (g == 0) ? c1 : (g == 1 ? c2 : c3);
    int* off = (g == 0) ? o1 : (g == 1 ? o2 : o3);
    int n = (g == 2) ? ITEM : KNOW;
    int tid = threadIdx.x, lane = tid & 63, wid = tid >> 6;
    int L = (n + 1023) >> 10;
    int i0 = tid * L;
    int sum = 0;
    for (int q = 0; q < L; ++q) {
        int i = i0 + q;
        if (i < n) sum += cnt[i];
    }
    int x = sum;
#pragma unroll
    for (int d = 1; d < 64; d <<= 1) { int t = __shfl_up(x, d, 64); if (lane >= d) x += t; }
    __shared__ int ws[16];
    if (lane == 63) ws[wid] = x;
    __syncthreads();
    if (wid == 0) {
        int w = (lane < 16) ? ws[lane] : 0;
#pragma unroll
        for (int d = 1; d < 16; d <<= 1) { int t = __shfl_up(w, d, 64); if (lane >= d) w += t; }
        if (lane < 16) ws[lane] = w;
    }
    __syncthreads();
    int run = x - sum + ((wid > 0) ? ws[wid - 1] : 0);
    if (tid == 0) off[0] = 0;
    for (int q = 0; q < L; ++q) {
        int i = i0 + q;
        if (i < n) {
            int v = cnt[i];
            cnt[i] = run;
            run += v;
            off[i + 1] = run;
        }
    }
}

__global__ void scatter3(const int* __restrict__ s1, const int* __restrict__ d1,
                         const int* __restrict__ s2, const int* __restrict__ d2,
                         const int* __restrict__ s3, const int* __restrict__ d3,
                         int E1, int E2, int* __restrict__ cur1, int* __restrict__ cur2, int* __restrict__ cur3,
                         int* __restrict__ e1, int* __restrict__ e2, int* __restrict__ e3) {
    int i = blockIdx.x * blockDim.x + threadIdx.x;
    if (i < E1) { int p = atomicAdd(&cur1[d1[i]], 1); e1[p] = s1[i]; }
    else if (i < E1 + E2) { int j = i - E1; int d = d2[j]; if (d >= ITEM) { int p = atomicAdd(&cur2[d - ITEM], 1); e2[p] = s2[j]; } }
    else if (i < E1 + 2 * E2) { int j = i - E1 - E2; int d = d3[j]; if (d < ITEM) { int p = atomicAdd(&cur3[d], 1); e3[p] = s3[j]; } }
}

// ---------------- per-row attention aggregation, 4-way edge-parallel ----------------
__device__ __forceinline__ void agg_row(const float* __restrict__ Z, const float* __restrict__ dsrc,
                                        float dd, const int* __restrict__ es, int e0, int e1,
                                        int lane, float* __restrict__ acc) {
#pragma unroll
    for (int q = 0; q < 8; ++q) acc[q] = 0.f;
    if (e1 <= e0) return;
    float mx = -3.4e38f;
    for (int e = e0 + lane; e < e1; e += 64) {
        float t = dsrc[es[e]] + dd;
        t = (t > 0.f) ? t : 0.01f * t;
        mx = fmaxf(mx, t);
    }
#pragma unroll
    for (int o = 32; o; o >>= 1) mx = fmaxf(mx, __shfl_xor(mx, o, 64));
    int eg = lane >> 4, cs = lane & 15;
    float den = 0.f;
    for (int e = e0 + eg; e < e1; e += 4) {
        int s = es[e];
        float t = dsrc[s] + dd;
        t = (t > 0.f) ? t : 0.01f * t;
        float w = __expf(t - mx);
        den += w;
        const float4* zr = (const float4*)(Z + (size_t)s * D + cs * 8);
        float4 za = zr[0], zb = zr[1];
        acc[0] = fmaf(w, za.x, acc[0]); acc[1] = fmaf(w, za.y, acc[1]);
        acc[2] = fmaf(w, za.z, acc[2]); acc[3] = fmaf(w, za.w, acc[3]);
        acc[4] = fmaf(w, zb.x, acc[4]); acc[5] = fmaf(w, zb.y, acc[5]);
        acc[6] = fmaf(w, zb.z, acc[6]); acc[7] = fmaf(w, zb.w, acc[7]);
    }
#pragma unroll
    for (int m = 16; m <= 32; m <<= 1) {
        den += __shfl_xor(den, m, 64);
#pragma unroll
        for (int q = 0; q < 8; ++q) acc[q] += __shfl_xor(acc[q], m, 64);
    }
    float inv = 1.f / fmaxf(den, 1e-12f);
#pragma unroll
    for (int q = 0; q < 8; ++q) acc[q] *= inv;
}

// ---------------- agg + fused ra-gate combine; optional krow tail blocks ----------------
__global__ __launch_bounds__(256) void agg3c(
    const float* __restrict__ z1, const float* __restrict__ z2, const float* __restrict__ z3,
    const float* __restrict__ ds1, const float* __restrict__ dd1,
    const float* __restrict__ ds2, const float* __restrict__ dd2,
    const float* __restrict__ ds3, const float* __restrict__ dd3,
    const int* __restrict__ off1, const int* __restrict__ es1,
    const int* __restrict__ off2, const int* __restrict__ es2,
    const int* __restrict__ off3, const int* __restrict__ es3,
    const float* __restrict__ raW1L, const float* __restrict__ raB1L,
    const float* __restrict__ raW2L, float* __restrict__ buf,
    const float* __restrict__ kn_rec, const float* __restrict__ kn_num,
    const int* __restrict__ p_target, float* __restrict__ krowP)
{
    int wv = threadIdx.x >> 6, lane = threadIdx.x & 63;
    int eg = lane >> 4, cs = lane & 15;
    int u = blockIdx.x;
    if (u < KNOW / 4) {
        __shared__ float ABs[4][2][D];
        int i = u * 4 + wv;
        float accA[8], accB[8];
        agg_row(z1, ds1, dd1[i], es1, off1[i], off1[i + 1], lane, accA);
        agg_row(z2, ds2, dd2[ITEM + i], es2, off2[i], off2[i + 1], lane, accB);
        if (eg == 0) {
            *(float4*)&ABs[wv][0][cs * 8]     = make_float4(accA[0], accA[1], accA[2], accA[3]);
            *(float4*)&ABs[wv][0][cs * 8 + 4] = make_float4(accA[4], accA[5], accA[6], accA[7]);
            *(float4*)&ABs[wv][1][cs * 8]     = make_float4(accB[0], accB[1], accB[2], accB[3]);
            *(float4*)&ABs[wv][1][cs * 8 + 4] = make_float4(accB[4], accB[5], accB[6], accB[7]);
        }
        __syncthreads();
        int j0 = lane * 2;
        float b0 = raB1L[j0], b1 = raB1L[j0 + 1];
        float aA0 = b0, aA1 = b1, aB0 = b0, aB1 = b1;
#pragma unroll 4
        for (int k = 0; k < D; ++k) {
            float av = ABs[wv][0][k], bv = ABs[wv][1][k];
            float2 w = *(const float2*)(raW1L + (size_t)k * D + j0);
            aA0 = fmaf(av, w.x, aA0); aA1 = fmaf(av, w.y, aA1);
            aB0 = fmaf(bv, w.x, aB0); aB1 = fmaf(bv, w.y, aB1);
        }
        float2 w2 = *(const float2*)(raW2L + j0);
        float pA = tanhf(aA0) * w2.x + tanhf(aA1) * w2.y;
        float pB = tanhf(aB0) * w2.x + tanhf(aB1) * w2.y;
#pragma unroll
        for (int o = 32; o; o >>= 1) { pA += __shfl_xor(pA, o, 64); pB += __shfl_xor(pB, o, 64); }
        float mx2 = fmaxf(pA, pB);
        float eA = __expf(pA - mx2), eB = __expf(pB - mx2);
        float s = 1.f / (eA + eB);
        float sA = eA * s, sB = eB * s;
        float2 Av = *(float2*)&ABs[wv][0][j0];
        float2 Bv = *(float2*)&ABs[wv][1][j0];
        *(float2*)(buf + (size_t)(ITEM + i) * D + j0) =
            make_float2(sA * Av.x + sB * Bv.x, sA * Av.y + sB * Bv.y);
    } else if (u < NAGGU) {
        int row = (u - KNOW / 4) * 4 + wv;
        if (row < ITEM) {
            float acc[8];
            agg_row(z3, ds3, dd3[row], es3, off3[row], off3[row + 1], lane, acc);
            if (eg == 0) {
                *(float4*)(buf + (size_t)row * D + cs * 8)     = make_float4(acc[0], acc[1], acc[2], acc[3]);
                *(float4*)(buf + (size_t)row * D + cs * 8 + 4) = make_float4(acc[4], acc[5], acc[6], acc[7]);
            }
        }
    } else {
        // krow tail blocks (layer-0 launch only): independent HBM-streaming work
        int uk = u - NAGGU;
        int b = uk & (BB - 1), ch = uk >> 8;
        int cnt = p_target[b] + 1;
        int per = (SS + CH - 1) / CH;
        int s0 = ch * per, s1 = s0 + per;
        if (s1 > cnt) s1 = cnt;
        int k0 = threadIdx.x * 4;
        float4 a = make_float4(0.f, 0.f, 0.f, 0.f);
        for (int s = s0; s < s1; ++s) {
            float inv = 1.f / kn_num[b * SS + s];
            float4 v = *(const float4*)(kn_rec + ((size_t)b * SS + s) * KNOW + k0);
            a.x += v.x * inv; a.y += v.y * inv; a.z += v.z * inv; a.w += v.w * inv;
        }
        *(float4*)(krowP + ((size_t)ch * BB + b) * KNOW + k0) = a;
    }
}

// ---------------- h assembly: [be_mean | ba_mean | (krow@kn)/msum] ----------------
__global__ __launch_bounds__(512) void hker(const float* __restrict__ ex, const float* __restrict__ ans_table,
                                            const int* __restrict__ p_rec, const int* __restrict__ a_rec,
                                            const int* __restrict__ p_target, const float* __restrict__ krowP,
                                            const float* __restrict__ kn, float* __restrict__ h) {
    int b = blockIdx.x;
    int j = threadIdx.x & 127, sg = threadIdx.x >> 7;
    int cnt = p_target[b] + 1;
    __shared__ int pidx[SS], aidx[SS];
    __shared__ float kr[KNOW];
    __shared__ float red[4][3][128];
    for (int i = threadIdx.x; i < cnt; i += 512) { pidx[i] = p_rec[b * SS + i]; aidx[i] = a_rec[b * SS + i]; }
    for (int i = threadIdx.x; i < KNOW; i += 512) {
        float s = 0.f;
#pragma unroll
        for (int c = 0; c < CH; ++c) s += krowP[((size_t)c * BB + b) * KNOW + i];
        kr[i] = s;
    }
    __syncthreads();
    float accE = 0.f, accA = 0.f;
    for (int s = sg; s < cnt; s += 4) {
        accE += ex[(size_t)pidx[s] * D + j];
        accA += ans_table[aidx[s] * D + j];
    }
    float accK = 0.f;
    for (int k = sg * 256; k < sg * 256 + 256; ++k) accK += kr[k] * kn[(size_t)k * D + j];
    red[sg][0][j] = accE; red[sg][1][j] = accA; red[sg][2][j] = accK;
    __syncthreads();
    if (sg == 0) {
        float inv = 1.f / (float)cnt;
        float e = (red[0][0][j] + red[1][0][j] + red[2][0][j] + red[3][0][j]) * inv;
        float a = (red[0][1][j] + red[1][1][j] + red[2][1][j] + red[3][1][j]) * inv;
        float kv = (red[0][2][j] + red[1][2][j] + red[2][2][j] + red[3][2][j]) * inv;
        h[b * H3 + j] = e;
        h[b * H3 + D + j] = a;
        h[b * H3 + 2 * D + j] = kv;
    }
}

// ---------------- unified hidden GEMM: tanh(h @ [actW1|vW1]) for all 4 heads ----------------
__global__ __launch_bounds__(256) void hidden_gemm(const float* __restrict__ h,
                                                   const float* __restrict__ actW1, const float* __restrict__ actB1,
                                                   const float* __restrict__ vW1, const float* __restrict__ vB1,
                                                   float* __restrict__ hid) {
    __shared__ float hT[H3 * 17];
    int tid = threadIdx.x;
    int b0 = blockIdx.y * 16;
    for (int idx = tid; idx < 16 * H3; idx += 256) {
        int r = idx / H3, k = idx - r * H3;
        hT[k * 17 + r] = h[(size_t)(b0 + r) * H3 + k];
    }
    __syncthreads();
    int j = blockIdx.x * 64 + (tid & 63);
    int head = j >> 8, jj = j & 255;
    int rg = tid >> 6, r0 = rg * 4;
    const float* W = (head == 0) ? actW1 : (vW1 + (size_t)(head - 1) * H3 * LAT);
    float bias = (head == 0) ? actB1[jj] : vB1[(head - 1) * LAT + jj];
    float acc[4] = {bias, bias, bias, bias};
#pragma unroll 4
    for (int k = 0; k < H3; ++k) {
        float w = W[(size_t)k * LAT + jj];
        float h0 = hT[k * 17 + r0 + 0];
        float h1 = hT[k * 17 + r0 + 1];
        float h2 = hT[k * 17 + r0 + 2];
        float h3 = hT[k * 17 + r0 + 3];
        acc[0] = fmaf(h0, w, acc[0]);
        acc[1] = fmaf(h1, w, acc[1]);
        acc[2] = fmaf(h2, w, acc[2]);
        acc[3] = fmaf(h3, w, acc[3]);
    }
#pragma unroll
    for (int r = 0; r < 4; ++r)
        hid[((size_t)head * BB + (b0 + r0 + r)) * LAT + jj] = tanhf(acc[r]);
}

// ---------------- logits GEMM + value heads (merged; both read only hid) ----------------
__global__ __launch_bounds__(256) void logitsvals(const float* __restrict__ hid,
                                                  const float* __restrict__ actW2, const float* __restrict__ actB2,
                                                  const float* __restrict__ vW2, const float* __restrict__ vB2,
                                                  float* __restrict__ out) {
    int bid = blockIdx.x;
    int tid = threadIdx.x;
    if (bid < NLV) {
        __shared__ float hT[LAT * 33];
        int ix = bid % NLOGB, iy = bid / NLOGB;
        int b0 = iy * 32;
        for (int idx = tid; idx < 32 * LAT; idx += 256) {
            int r = idx >> 8, k = idx & 255;
            hT[k * 33 + r] = hid[(size_t)(b0 + r) * LAT + k];
        }
        __syncthreads();
        int lane6 = tid & 63;
        int rg = tid >> 6, r0 = rg * 8;
        int ibase = ix * 256 + lane6;
        int icol[4], icl[4];
        float bias[4];
#pragma unroll
        for (int c = 0; c < 4; ++c) {
            icol[c] = ibase + c * 64;
            icl[c] = icol[c] < ITEM ? icol[c] : (ITEM - 1);
            bias[c] = actB2[icl[c]];
        }
        float acc[8][4];
#pragma unroll
        for (int r = 0; r < 8; ++r)
#pragma unroll
            for (int c = 0; c < 4; ++c) acc[r][c] = bias[c];
#pragma unroll 2
        for (int k = 0; k < LAT; ++k) {
            float w0 = actW2[(size_t)k * ITEM + icl[0]];
            float w1 = actW2[(size_t)k * ITEM + icl[1]];
            float w2 = actW2[(size_t)k * ITEM + icl[2]];
            float w3 = actW2[(size_t)k * ITEM + icl[3]];
            const float* hp = &hT[k * 33 + r0];
#pragma unroll
            for (int r = 0; r < 8; ++r) {
                float hv = hp[r];
                acc[r][0] = fmaf(hv, w0, acc[r][0]);
                acc[r][1] = fmaf(hv, w1, acc[r][1]);
                acc[r][2] = fmaf(hv, w2, acc[r][2]);
                acc[r][3] = fmaf(hv, w3, acc[r][3]);
            }
        }
#pragma unroll
        for (int c = 0; c < 4; ++c) {
            if (icol[c] < ITEM) {
#pragma unroll
                for (int r = 0; r < 8; ++r)
                    out[(size_t)(b0 + r0 + r) * ITEM + icol[c]] = acc[r][c];
            }
        }
    } else {
        int idx = (bid - NLV) * 4 + (tid >> 6);
        int lane = tid & 63;
        if (idx >= 3 * BB) return;
        int k = idx / BB, b = idx - k * BB;
        const float* vh = hid + ((size_t)(k + 1) * BB + b) * LAT;
        float4 a = ((const float4*)vh)[lane];
        float4 w = ((const float4*)(vW2 + k * LAT))[lane];
        float s = a.x * w.x + a.y * w.y + a.z * w.z + a.w * w.w;
#pragma unroll
        for (int o = 32; o; o >>= 1) s += __shfl_down(s, o, 64);
        if (lane == 0) out[(size_t)BB * ITEM + k * BB + b] = s + vB2[k];
    }
}

extern "C" void kernel_launch(void* const* d_in, const int* in_sizes, int n_in,
                              void* d_out, int out_size, void* d_ws, size_t ws_size,
                              hipStream_t stream) {
    const int*   p_rec      = (const int*)d_in[0];
    const int*   p_target   = (const int*)d_in[1];
    const int*   a_rec      = (const int*)d_in[2];
    const float* kn_rec     = (const float*)d_in[3];
    const float* kn_num     = (const float*)d_in[4];
    const int*   src1       = (const int*)d_in[5];
    const int*   dst1       = (const int*)d_in[6];
    const int*   src2       = (const int*)d_in[7];
    const int*   dst2       = (const int*)d_in[8];
    const int*   src3       = (const int*)d_in[9];
    const int*   dst3       = (const int*)d_in[10];
    const float* kn_table   = (const float*)d_in[11];
    const float* exer_table = (const float*)d_in[12];
    const float* ans_table  = (const float*)d_in[13];
    const float* gW         = (const float*)d_in[14];
    const float* gA         = (const float*)d_in[15];
    const float* raW1       = (const float*)d_in[16];
    const float* raB1       = (const float*)d_in[17];
    const float* raW2       = (const float*)d_in[18];
    const float* actW1      = (const float*)d_in[19];
    const float* actB1      = (const float*)d_in[20];
    const float* actW2      = (const float*)d_in[21];
    const float* actB2      = (const float*)d_in[22];
    const float* vW1        = (const float*)d_in[23];
    const float* vB1        = (const float*)d_in[24];
    const float* vW2        = (const float*)d_in[25];
    const float* vB2        = (const float*)d_in[26];
    const int E1 = in_sizes[5], E2 = in_sizes[7];

    float* base = (float*)d_ws;
    size_t o = 0;
    auto alloc = [&](size_t n) -> float* { float* p = base + o; o += (n + 3) & ~(size_t)3; return p; };
    float* buf  = alloc((size_t)NTOT * D);
    float* z1   = alloc((size_t)KNOW * D);
    float* z2   = alloc((size_t)NTOT * D);
    float* z3   = alloc((size_t)NTOT * D);
    float* ds1 = alloc(KNOW);  float* dd1 = alloc(KNOW);
    float* ds2 = alloc(NTOT);  float* dd2 = alloc(NTOT);
    float* ds3 = alloc(NTOT);  float* dd3 = alloc(NTOT);
    int* cnts = (int*)alloc(2 * KNOW + NTOT);
    int* cnt1 = cnts, *cnt2 = cnts + KNOW, *cnt3 = cnts + 2 * KNOW;
    int* off1 = (int*)alloc(KNOW + 1);
    int* off2 = (int*)alloc(KNOW + 1);
    int* off3 = (int*)alloc(ITEM + 1);
    int* es1  = (int*)alloc(E1);
    int* es2  = (int*)alloc(E2);
    int* es3  = (int*)alloc(E2);
    float* krowP = alloc((size_t)CH * BB * KNOW);
    float* hbuf  = alloc((size_t)BB * H3);
    float* hid   = alloc((size_t)4 * BB * LAT);

    hipMemsetAsync(cnts, 0, sizeof(int) * (2 * KNOW + NTOT), stream);

    int etot = E1 + 2 * E2;
    hist3<<<(etot + 255) / 256, 256, 0, stream>>>(dst1, dst2, dst3, E1, E2, cnt1, cnt2, cnt3);
    exscan3<<<3, 1024, 0, stream>>>(cnt1, off1, cnt2, off2, cnt3, off3);
    scatter3<<<(etot + 255) / 256, 256, 0, stream>>>(src1, dst1, src2, dst2, src3, dst3,
                                                     E1, E2, cnt1, cnt2, cnt3, es1, es2, es3);

    for (int l = 0; l < LAYERS; ++l) {
        const float* Xe = (l == 0) ? exer_table : buf;
        const float* Xk = (l == 0) ? kn_table : (buf + (size_t)ITEM * D);
        zdv_ker<<<NZT, 256, 0, stream>>>(Xe, Xk, gW, gA, l, z1, z2, z3,
                                         ds1, dd1, ds2, dd2, ds3, dd3);
        int nb = NAGGU + ((l == 0) ? NKROW : 0);   // krow units ride along with layer-0 agg
        agg3c<<<nb, 256, 0, stream>>>(z1, z2, z3, ds1, dd1, ds2, dd2, ds3, dd3,
                                      off1, es1, off2, es2, off3, es3,
                                      raW1 + (size_t)l * D * D, raB1 + (size_t)l * D,
                                      raW2 + (size_t)l * D, buf,
                                      kn_rec, kn_num, p_target, krowP);
    }
    // ex = buf[:ITEM], kn = buf[ITEM:]

    hker<<<BB, 512, 0, stream>>>(buf, ans_table, p_rec, a_rec, p_target, krowP, buf + (size_t)ITEM * D, hbuf);
    hidden_gemm<<<dim3(16, 16), 256, 0, stream>>>(hbuf, actW1, actB1, vW1, vB1, hid);
    logitsvals<<<NLV + NVB, 256, 0, stream>>>(hid, actW2, actB2, vW2, vB2, (float*)d_out);
}

// Round 18
// 298.690 us; speedup vs baseline: 2.3405x; 1.0162x over previous
//
#include <hip/hip_runtime.h>

#define D 128
#define KNOW 1024
#define ITEM 20000
#define NTOT (ITEM + KNOW)
#define LAYERS 2
#define LAT 256
#define BB 256
#define SS 200
#define H3 (3 * D)
#define CH 4
#define ZROWS 64
#define NBK (KNOW / ZROWS)                 // 16
#define NBN ((NTOT + ZROWS - 1) / ZROWS)   // 329
#define NZT (NBK + 2 * NBN)                // 674 zdv tiles
#define NAGGU (KNOW / 4 + ITEM / 4)        // 5256 agg units
#define NKROW (BB * CH)                    // 1024 krow units
#define XPITCH 68
#define NLOGB ((ITEM + 255) / 256)         // 79
#define NLV (NLOGB * (BB / 32))            // 632 logits blocks
#define NVB ((3 * BB + 3) / 4)             // 192 vals blocks

// ---------------- fused z = X@W plus dvec (dsrc/ddst) for all 3 graphs ----------------
__global__ __launch_bounds__(256) void zdv_ker(
    const float* __restrict__ Xe, const float* __restrict__ Xk,
    const float* __restrict__ gW, const float* __restrict__ gA, int layer,
    float* __restrict__ z1, float* __restrict__ z2, float* __restrict__ z3,
    float* __restrict__ ds1, float* __restrict__ dd1,
    float* __restrict__ ds2, float* __restrict__ dd2,
    float* __restrict__ ds3, float* __restrict__ dd3)
{
    __shared__ __align__(16) float xT[D * XPITCH];   // 34.8 KB
    int bid = blockIdx.x;
    int g, row0, nmax;
    if (bid < NBK)            { g = 0; row0 = bid * ZROWS;                nmax = KNOW; }
    else if (bid < NBK + NBN) { g = 1; row0 = (bid - NBK) * ZROWS;        nmax = NTOT; }
    else                      { g = 2; row0 = (bid - NBK - NBN) * ZROWS;  nmax = NTOT; }
    const float* W = gW + (size_t)(layer * 3 + g) * D * D;
    const float* A = gA + (size_t)(layer * 3 + g) * 2 * D;
    float* Z  = (g == 0) ? z1  : (g == 1 ? z2  : z3);
    float* DS = (g == 0) ? ds1 : (g == 1 ? ds2 : ds3);
    float* DD = (g == 0) ? dd1 : (g == 1 ? dd2 : dd3);

    int tid = threadIdx.x;
#pragma unroll
    for (int i = 0; i < 8; ++i) {
        int flat = tid + i * 256;
        int row  = flat >> 5;
        int f4   = flat & 31;
        int grow = row0 + row;
        float4 v = make_float4(0.f, 0.f, 0.f, 0.f);
        if (grow < nmax) {
            const float* src = (g == 0) ? (Xk + (size_t)grow * D)
                             : (grow < ITEM ? Xe + (size_t)grow * D
                                            : Xk + (size_t)(grow - ITEM) * D);
            v = *(const float4*)(src + f4 * 4);
        }
        int slot = row ^ ((f4 & 7) << 2);
        int kk = f4 * 4;
        xT[(kk + 0) * XPITCH + slot] = v.x;
        xT[(kk + 1) * XPITCH + slot] = v.y;
        xT[(kk + 2) * XPITCH + slot] = v.z;
        xT[(kk + 3) * XPITCH + slot] = v.w;
    }
    __syncthreads();

    int cg_ = tid & 31;
    int rg = tid >> 5;
    int c0 = cg_ * 4;
    int r0a = rg * 8, r0b = rg * 8 + 4;

    float acc[8][4];
#pragma unroll
    for (int r = 0; r < 8; ++r)
#pragma unroll
        for (int c = 0; c < 4; ++c) acc[r][c] = 0.f;

#pragma unroll 4
    for (int k = 0; k < D; ++k) {
        float4 wv = *(const float4*)(W + (size_t)k * D + c0);
        int xc = ((k >> 2) & 7) << 2;
        float4 xa = *(const float4*)&xT[k * XPITCH + (r0a ^ xc)];
        float4 xb = *(const float4*)&xT[k * XPITCH + (r0b ^ xc)];
        acc[0][0] = fmaf(xa.x, wv.x, acc[0][0]); acc[0][1] = fmaf(xa.x, wv.y, acc[0][1]);
        acc[0][2] = fmaf(xa.x, wv.z, acc[0][2]); acc[0][3] = fmaf(xa.x, wv.w, acc[0][3]);
        acc[1][0] = fmaf(xa.y, wv.x, acc[1][0]); acc[1][1] = fmaf(xa.y, wv.y, acc[1][1]);
        acc[1][2] = fmaf(xa.y, wv.z, acc[1][2]); acc[1][3] = fmaf(xa.y, wv.w, acc[1][3]);
        acc[2][0] = fmaf(xa.z, wv.x, acc[2][0]); acc[2][1] = fmaf(xa.z, wv.y, acc[2][1]);
        acc[2][2] = fmaf(xa.z, wv.z, acc[2][2]); acc[2][3] = fmaf(xa.z, wv.w, acc[2][3]);
        acc[3][0] = fmaf(xa.w, wv.x, acc[3][0]); acc[3][1] = fmaf(xa.w, wv.y, acc[3][1]);
        acc[3][2] = fmaf(xa.w, wv.z, acc[3][2]); acc[3][3] = fmaf(xa.w, wv.w, acc[3][3]);
        acc[4][0] = fmaf(xb.x, wv.x, acc[4][0]); acc[4][1] = fmaf(xb.x, wv.y, acc[4][1]);
        acc[4][2] = fmaf(xb.x, wv.z, acc[4][2]); acc[4][3] = fmaf(xb.x, wv.w, acc[4][3]);
        acc[5][0] = fmaf(xb.y, wv.x, acc[5][0]); acc[5][1] = fmaf(xb.y, wv.y, acc[5][1]);
        acc[5][2] = fmaf(xb.y, wv.z, acc[5][2]); acc[5][3] = fmaf(xb.y, wv.w, acc[5][3]);
        acc[6][0] = fmaf(xb.z, wv.x, acc[6][0]); acc[6][1] = fmaf(xb.z, wv.y, acc[6][1]);
        acc[6][2] = fmaf(xb.z, wv.z, acc[6][2]); acc[6][3] = fmaf(xb.z, wv.w, acc[6][3]);
        acc[7][0] = fmaf(xb.w, wv.x, acc[7][0]); acc[7][1] = fmaf(xb.w, wv.y, acc[7][1]);
        acc[7][2] = fmaf(xb.w, wv.z, acc[7][2]); acc[7][3] = fmaf(xb.w, wv.w, acc[7][3]);
    }

#pragma unroll
    for (int r = 0; r < 8; ++r) {
        int grow = row0 + ((r < 4) ? (r0a + r) : (r0b + r - 4));
        if (grow < nmax) {
            float4 v = make_float4(acc[r][0], acc[r][1], acc[r][2], acc[r][3]);
            *(float4*)(Z + (size_t)grow * D + c0) = v;
        }
    }

    float4 as = *(const float4*)(A + c0);
    float4 ad = *(const float4*)(A + D + c0);
    float ps[8], pd[8];
#pragma unroll
    for (int r = 0; r < 8; ++r) {
        ps[r] = acc[r][0] * as.x + acc[r][1] * as.y + acc[r][2] * as.z + acc[r][3] * as.w;
        pd[r] = acc[r][0] * ad.x + acc[r][1] * ad.y + acc[r][2] * ad.z + acc[r][3] * ad.w;
    }
#pragma unroll
    for (int m = 16; m; m >>= 1) {
#pragma unroll
        for (int r = 0; r < 8; ++r) {
            ps[r] += __shfl_xor(ps[r], m, 64);
            pd[r] += __shfl_xor(pd[r], m, 64);
        }
    }
    if (cg_ == 0) {
#pragma unroll
        for (int r = 0; r < 8; ++r) {
            int grow = row0 + ((r < 4) ? (r0a + r) : (r0b + r - 4));
            if (grow < nmax) { DS[grow] = ps[r]; DD[grow] = pd[r]; }
        }
    }
}

// ---------------- CSR build (graph2: dst >= ITEM; graph3: dst < ITEM) ----------------
__global__ void hist3(const int* __restrict__ d1, const int* __restrict__ d2, const int* __restrict__ d3,
                      int E1, int E2, int* __restrict__ c1, int* __restrict__ c2, int* __restrict__ c3) {
    int i = blockIdx.x * blockDim.x + threadIdx.x;
    if (i < E1) atomicAdd(&c1[d1[i]], 1);
    else if (i < E1 + E2) { int d = d2[i - E1]; if (d >= ITEM) atomicAdd(&c2[d - ITEM], 1); }
    else if (i < E1 + 2 * E2) { int d = d3[i - E1 - E2]; if (d < ITEM) atomicAdd(&c3[d], 1); }
}

// Thread-chunked exclusive scan: 2 barriers total.
__global__ __launch_bounds__(1024) void exscan3(int* __restrict__ c1, int* __restrict__ o1,
                                                int* __restrict__ c2, int* __restrict__ o2,
                                                int* __restrict__ c3, int* __restrict__ o3) {
    int g = blockIdx.x;
    int* cnt = (g == 0) ? c1 : (g == 1 ? c2 : c3);
    int* off = (g == 0) ? o1 : (g == 1 ? o2 : o3);
    int n = (g == 2) ? ITEM : KNOW;
    int tid = threadIdx.x, lane = tid & 63, wid = tid >> 6;
    int L = (n + 1023) >> 10;
    int i0 = tid * L;
    int sum = 0;
    for (int q = 0; q < L; ++q) {
        int i = i0 + q;
        if (i < n) sum += cnt[i];
    }
    int x = sum;
#pragma unroll
    for (int d = 1; d < 64; d <<= 1) { int t = __shfl_up(x, d, 64); if (lane >= d) x += t; }
    __shared__ int ws[16];
    if (lane == 63) ws[wid] = x;
    __syncthreads();
    if (wid == 0) {
        int w = (lane < 16) ? ws[lane] : 0;
#pragma unroll
        for (int d = 1; d < 16; d <<= 1) { int t = __shfl_up(w, d, 64); if (lane >= d) w += t; }
        if (lane < 16) ws[lane] = w;
    }
    __syncthreads();
    int run = x - sum + ((wid > 0) ? ws[wid - 1] : 0);
    if (tid == 0) off[0] = 0;
    for (int q = 0; q < L; ++q) {
        int i = i0 + q;
        if (i < n) {
            int v = cnt[i];
            cnt[i] = run;
            run += v;
            off[i + 1] = run;
        }
    }
}

__global__ void scatter3(const int* __restrict__ s1, const int* __restrict__ d1,
                         const int* __restrict__ s2, const int* __restrict__ d2,
                         const int* __restrict__ s3, const int* __restrict__ d3,
                         int E1, int E2, int* __restrict__ cur1, int* __restrict__ cur2, int* __restrict__ cur3,
                         int* __restrict__ e1, int* __restrict__ e2, int* __restrict__ e3) {
    int i = blockIdx.x * blockDim.x + threadIdx.x;
    if (i < E1) { int p = atomicAdd(&cur1[d1[i]], 1); e1[p] = s1[i]; }
    else if (i < E1 + E2) { int j = i - E1; int d = d2[j]; if (d >= ITEM) { int p = atomicAdd(&cur2[d - ITEM], 1); e2[p] = s2[j]; } }
    else if (i < E1 + 2 * E2) { int j = i - E1 - E2; int d = d3[j]; if (d < ITEM) { int p = atomicAdd(&cur3[d], 1); e3[p] = s3[j]; } }
}

// ---------------- per-row attention aggregation, single-pass (softmax shift-invariance:
// exp(e-m)/sum == exp(e)/sum exactly; |e| << 1 here so no overflow risk) ----------------
__device__ __forceinline__ void agg_row(const float* __restrict__ Z, const float* __restrict__ dsrc,
                                        float dd, const int* __restrict__ es, int e0, int e1,
                                        int lane, float* __restrict__ acc, float& den) {
#pragma unroll
    for (int q = 0; q < 8; ++q) acc[q] = 0.f;
    den = 0.f;
    if (e1 <= e0) return;
    int eg = lane >> 4, cs = lane & 15;
#pragma unroll 2
    for (int e = e0 + eg; e < e1; e += 4) {
        int s = es[e];
        float t = dsrc[s] + dd;
        t = (t > 0.f) ? t : 0.01f * t;
        float w = __expf(t);
        den += w;
        const float4* zr = (const float4*)(Z + (size_t)s * D + cs * 8);
        float4 za = zr[0], zb = zr[1];
        acc[0] = fmaf(w, za.x, acc[0]); acc[1] = fmaf(w, za.y, acc[1]);
        acc[2] = fmaf(w, za.z, acc[2]); acc[3] = fmaf(w, za.w, acc[3]);
        acc[4] = fmaf(w, zb.x, acc[4]); acc[5] = fmaf(w, zb.y, acc[5]);
        acc[6] = fmaf(w, zb.z, acc[6]); acc[7] = fmaf(w, zb.w, acc[7]);
    }
#pragma unroll
    for (int m = 16; m <= 32; m <<= 1) {
        den += __shfl_xor(den, m, 64);
#pragma unroll
        for (int q = 0; q < 8; ++q) acc[q] += __shfl_xor(acc[q], m, 64);
    }
    float inv = 1.f / fmaxf(den, 1e-12f);
#pragma unroll
    for (int q = 0; q < 8; ++q) acc[q] *= inv;
}

// ---------------- agg + fused ra-gate combine; optional krow tail blocks ----------------
__global__ __launch_bounds__(256) void agg3c(
    const float* __restrict__ z1, const float* __restrict__ z2, const float* __restrict__ z3,
    const float* __restrict__ ds1, const float* __restrict__ dd1,
    const float* __restrict__ ds2, const float* __restrict__ dd2,
    const float* __restrict__ ds3, const float* __restrict__ dd3,
    const int* __restrict__ off1, const int* __restrict__ es1,
    const int* __restrict__ off2, const int* __restrict__ es2,
    const int* __restrict__ off3, const int* __restrict__ es3,
    const float* __restrict__ raW1L, const float* __restrict__ raB1L,
    const float* __restrict__ raW2L, float* __restrict__ buf,
    const float* __restrict__ kn_rec, const float* __restrict__ kn_num,
    const int* __restrict__ p_target, float* __restrict__ krowP)
{
    int wv = threadIdx.x >> 6, lane = threadIdx.x & 63;
    int eg = lane >> 4, cs = lane & 15;
    int u = blockIdx.x;
    if (u < KNOW / 4) {
        __shared__ float ABs[4][2][D];
        int i = u * 4 + wv;
        float accA[8], accB[8];
        float denA, denB;
        agg_row(z1, ds1, dd1[i], es1, off1[i], off1[i + 1], lane, accA, denA);
        agg_row(z2, ds2, dd2[ITEM + i], es2, off2[i], off2[i + 1], lane, accB, denB);
        if (eg == 0) {
            *(float4*)&ABs[wv][0][cs * 8]     = make_float4(accA[0], accA[1], accA[2], accA[3]);
            *(float4*)&ABs[wv][0][cs * 8 + 4] = make_float4(accA[4], accA[5], accA[6], accA[7]);
            *(float4*)&ABs[wv][1][cs * 8]     = make_float4(accB[0], accB[1], accB[2], accB[3]);
            *(float4*)&ABs[wv][1][cs * 8 + 4] = make_float4(accB[4], accB[5], accB[6], accB[7]);
        }
        __syncthreads();
        int j0 = lane * 2;
        float b0 = raB1L[j0], b1 = raB1L[j0 + 1];
        float aA0 = b0, aA1 = b1, aB0 = b0, aB1 = b1;
#pragma unroll 4
        for (int k = 0; k < D; ++k) {
            float av = ABs[wv][0][k], bv = ABs[wv][1][k];
            float2 w = *(const float2*)(raW1L + (size_t)k * D + j0);
            aA0 = fmaf(av, w.x, aA0); aA1 = fmaf(av, w.y, aA1);
            aB0 = fmaf(bv, w.x, aB0); aB1 = fmaf(bv, w.y, aB1);
        }
        float2 w2 = *(const float2*)(raW2L + j0);
        float pA = tanhf(aA0) * w2.x + tanhf(aA1) * w2.y;
        float pB = tanhf(aB0) * w2.x + tanhf(aB1) * w2.y;
#pragma unroll
        for (int o = 32; o; o >>= 1) { pA += __shfl_xor(pA, o, 64); pB += __shfl_xor(pB, o, 64); }
        float mx2 = fmaxf(pA, pB);
        float eA = __expf(pA - mx2), eB = __expf(pB - mx2);
        float s = 1.f / (eA + eB);
        float sA = eA * s, sB = eB * s;
        float2 Av = *(float2*)&ABs[wv][0][j0];
        float2 Bv = *(float2*)&ABs[wv][1][j0];
        *(float2*)(buf + (size_t)(ITEM + i) * D + j0) =
            make_float2(sA * Av.x + sB * Bv.x, sA * Av.y + sB * Bv.y);
    } else if (u < NAGGU) {
        int row = (u - KNOW / 4) * 4 + wv;
        if (row < ITEM) {
            float acc[8];
            float den;
            agg_row(z3, ds3, dd3[row], es3, off3[row], off3[row + 1], lane, acc, den);
            if (eg == 0) {
                *(float4*)(buf + (size_t)row * D + cs * 8)     = make_float4(acc[0], acc[1], acc[2], acc[3]);
                *(float4*)(buf + (size_t)row * D + cs * 8 + 4) = make_float4(acc[4], acc[5], acc[6], acc[7]);
            }
        }
    } else {
        // krow tail blocks (layer-0 launch only): independent HBM-streaming work
        int uk = u - NAGGU;
        int b = uk & (BB - 1), ch = uk >> 8;
        int cnt = p_target[b] + 1;
        int per = (SS + CH - 1) / CH;
        int s0 = ch * per, s1 = s0 + per;
        if (s1 > cnt) s1 = cnt;
        int k0 = threadIdx.x * 4;
        float4 a = make_float4(0.f, 0.f, 0.f, 0.f);
        for (int s = s0; s < s1; ++s) {
            float inv = 1.f / kn_num[b * SS + s];
            float4 v = *(const float4*)(kn_rec + ((size_t)b * SS + s) * KNOW + k0);
            a.x += v.x * inv; a.y += v.y * inv; a.z += v.z * inv; a.w += v.w * inv;
        }
        *(float4*)(krowP + ((size_t)ch * BB + b) * KNOW + k0) = a;
    }
}

// ---------------- h assembly: [be_mean | ba_mean | (krow@kn)/msum] ----------------
__global__ __launch_bounds__(512) void hker(const float* __restrict__ ex, const float* __restrict__ ans_table,
                                            const int* __restrict__ p_rec, const int* __restrict__ a_rec,
                                            const int* __restrict__ p_target, const float* __restrict__ krowP,
                                            const float* __restrict__ kn, float* __restrict__ h) {
    int b = blockIdx.x;
    int j = threadIdx.x & 127, sg = threadIdx.x >> 7;
    int cnt = p_target[b] + 1;
    __shared__ int pidx[SS], aidx[SS];
    __shared__ float kr[KNOW];
    __shared__ float red[4][3][128];
    for (int i = threadIdx.x; i < cnt; i += 512) { pidx[i] = p_rec[b * SS + i]; aidx[i] = a_rec[b * SS + i]; }
    for (int i = threadIdx.x; i < KNOW; i += 512) {
        float s = 0.f;
#pragma unroll
        for (int c = 0; c < CH; ++c) s += krowP[((size_t)c * BB + b) * KNOW + i];
        kr[i] = s;
    }
    __syncthreads();
    float accE = 0.f, accA = 0.f;
    for (int s = sg; s < cnt; s += 4) {
        accE += ex[(size_t)pidx[s] * D + j];
        accA += ans_table[aidx[s] * D + j];
    }
    float accK = 0.f;
    for (int k = sg * 256; k < sg * 256 + 256; ++k) accK += kr[k] * kn[(size_t)k * D + j];
    red[sg][0][j] = accE; red[sg][1][j] = accA; red[sg][2][j] = accK;
    __syncthreads();
    if (sg == 0) {
        float inv = 1.f / (float)cnt;
        float e = (red[0][0][j] + red[1][0][j] + red[2][0][j] + red[3][0][j]) * inv;
        float a = (red[0][1][j] + red[1][1][j] + red[2][1][j] + red[3][1][j]) * inv;
        float kv = (red[0][2][j] + red[1][2][j] + red[2][2][j] + red[3][2][j]) * inv;
        h[b * H3 + j] = e;
        h[b * H3 + D + j] = a;
        h[b * H3 + 2 * D + j] = kv;
    }
}

// ---------------- unified hidden GEMM: tanh(h @ [actW1|vW1]) for all 4 heads ----------------
__global__ __launch_bounds__(256) void hidden_gemm(const float* __restrict__ h,
                                                   const float* __restrict__ actW1, const float* __restrict__ actB1,
                                                   const float* __restrict__ vW1, const float* __restrict__ vB1,
                                                   float* __restrict__ hid) {
    __shared__ float hT[H3 * 17];
    int tid = threadIdx.x;
    int b0 = blockIdx.y * 16;
    for (int idx = tid; idx < 16 * H3; idx += 256) {
        int r = idx / H3, k = idx - r * H3;
        hT[k * 17 + r] = h[(size_t)(b0 + r) * H3 + k];
    }
    __syncthreads();
    int j = blockIdx.x * 64 + (tid & 63);
    int head = j >> 8, jj = j & 255;
    int rg = tid >> 6, r0 = rg * 4;
    const float* W = (head == 0) ? actW1 : (vW1 + (size_t)(head - 1) * H3 * LAT);
    float bias = (head == 0) ? actB1[jj] : vB1[(head - 1) * LAT + jj];
    float acc[4] = {bias, bias, bias, bias};
#pragma unroll 4
    for (int k = 0; k < H3; ++k) {
        float w = W[(size_t)k * LAT + jj];
        float h0 = hT[k * 17 + r0 + 0];
        float h1 = hT[k * 17 + r0 + 1];
        float h2 = hT[k * 17 + r0 + 2];
        float h3 = hT[k * 17 + r0 + 3];
        acc[0] = fmaf(h0, w, acc[0]);
        acc[1] = fmaf(h1, w, acc[1]);
        acc[2] = fmaf(h2, w, acc[2]);
        acc[3] = fmaf(h3, w, acc[3]);
    }
#pragma unroll
    for (int r = 0; r < 4; ++r)
        hid[((size_t)head * BB + (b0 + r0 + r)) * LAT + jj] = tanhf(acc[r]);
}

// ---------------- logits GEMM + value heads (merged; both read only hid) ----------------
__global__ __launch_bounds__(256) void logitsvals(const float* __restrict__ hid,
                                                  const float* __restrict__ actW2, const float* __restrict__ actB2,
                                                  const float* __restrict__ vW2, const float* __restrict__ vB2,
                                                  float* __restrict__ out) {
    int bid = blockIdx.x;
    int tid = threadIdx.x;
    if (bid < NLV) {
        __shared__ float hT[LAT * 33];
        int ix = bid % NLOGB, iy = bid / NLOGB;
        int b0 = iy * 32;
        for (int idx = tid; idx < 32 * LAT; idx += 256) {
            int r = idx >> 8, k = idx & 255;
            hT[k * 33 + r] = hid[(size_t)(b0 + r) * LAT + k];
        }
        __syncthreads();
        int lane6 = tid & 63;
        int rg = tid >> 6, r0 = rg * 8;
        int ibase = ix * 256 + lane6;
        int icol[4], icl[4];
        float bias[4];
#pragma unroll
        for (int c = 0; c < 4; ++c) {
            icol[c] = ibase + c * 64;
            icl[c] = icol[c] < ITEM ? icol[c] : (ITEM - 1);
            bias[c] = actB2[icl[c]];
        }
        float acc[8][4];
#pragma unroll
        for (int r = 0; r < 8; ++r)
#pragma unroll
            for (int c = 0; c < 4; ++c) acc[r][c] = bias[c];
#pragma unroll 2
        for (int k = 0; k < LAT; ++k) {
            float w0 = actW2[(size_t)k * ITEM + icl[0]];
            float w1 = actW2[(size_t)k * ITEM + icl[1]];
            float w2 = actW2[(size_t)k * ITEM + icl[2]];
            float w3 = actW2[(size_t)k * ITEM + icl[3]];
            const float* hp = &hT[k * 33 + r0];
#pragma unroll
            for (int r = 0; r < 8; ++r) {
                float hv = hp[r];
                acc[r][0] = fmaf(hv, w0, acc[r][0]);
                acc[r][1] = fmaf(hv, w1, acc[r][1]);
                acc[r][2] = fmaf(hv, w2, acc[r][2]);
                acc[r][3] = fmaf(hv, w3, acc[r][3]);
            }
        }
#pragma unroll
        for (int c = 0; c < 4; ++c) {
            if (icol[c] < ITEM) {
#pragma unroll
                for (int r = 0; r < 8; ++r)
                    out[(size_t)(b0 + r0 + r) * ITEM + icol[c]] = acc[r][c];
            }
        }
    } else {
        int idx = (bid - NLV) * 4 + (tid >> 6);
        int lane = tid & 63;
        if (idx >= 3 * BB) return;
        int k = idx / BB, b = idx - k * BB;
        const float* vh = hid + ((size_t)(k + 1) * BB + b) * LAT;
        float4 a = ((const float4*)vh)[lane];
        float4 w = ((const float4*)(vW2 + k * LAT))[lane];
        float s = a.x * w.x + a.y * w.y + a.z * w.z + a.w * w.w;
#pragma unroll
        for (int o = 32; o; o >>= 1) s += __shfl_down(s, o, 64);
        if (lane == 0) out[(size_t)BB * ITEM + k * BB + b] = s + vB2[k];
    }
}

extern "C" void kernel_launch(void* const* d_in, const int* in_sizes, int n_in,
                              void* d_out, int out_size, void* d_ws, size_t ws_size,
                              hipStream_t stream) {
    const int*   p_rec      = (const int*)d_in[0];
    const int*   p_target   = (const int*)d_in[1];
    const int*   a_rec      = (const int*)d_in[2];
    const float* kn_rec     = (const float*)d_in[3];
    const float* kn_num     = (const float*)d_in[4];
    const int*   src1       = (const int*)d_in[5];
    const int*   dst1       = (const int*)d_in[6];
    const int*   src2       = (const int*)d_in[7];
    const int*   dst2       = (const int*)d_in[8];
    const int*   src3       = (const int*)d_in[9];
    const int*   dst3       = (const int*)d_in[10];
    const float* kn_table   = (const float*)d_in[11];
    const float* exer_table = (const float*)d_in[12];
    const float* ans_table  = (const float*)d_in[13];
    const float* gW         = (const float*)d_in[14];
    const float* gA         = (const float*)d_in[15];
    const float* raW1       = (const float*)d_in[16];
    const float* raB1       = (const float*)d_in[17];
    const float* raW2       = (const float*)d_in[18];
    const float* actW1      = (const float*)d_in[19];
    const float* actB1      = (const float*)d_in[20];
    const float* actW2      = (const float*)d_in[21];
    const float* actB2      = (const float*)d_in[22];
    const float* vW1        = (const float*)d_in[23];
    const float* vB1        = (const float*)d_in[24];
    const float* vW2        = (const float*)d_in[25];
    const float* vB2        = (const float*)d_in[26];
    const int E1 = in_sizes[5], E2 = in_sizes[7];

    float* base = (float*)d_ws;
    size_t o = 0;
    auto alloc = [&](size_t n) -> float* { float* p = base + o; o += (n + 3) & ~(size_t)3; return p; };
    float* buf  = alloc((size_t)NTOT * D);
    float* z1   = alloc((size_t)KNOW * D);
    float* z2   = alloc((size_t)NTOT * D);
    float* z3   = alloc((size_t)NTOT * D);
    float* ds1 = alloc(KNOW);  float* dd1 = alloc(KNOW);
    float* ds2 = alloc(NTOT);  float* dd2 = alloc(NTOT);
    float* ds3 = alloc(NTOT);  float* dd3 = alloc(NTOT);
    int* cnts = (int*)alloc(2 * KNOW + NTOT);
    int* cnt1 = cnts, *cnt2 = cnts + KNOW, *cnt3 = cnts + 2 * KNOW;
    int* off1 = (int*)alloc(KNOW + 1);
    int* off2 = (int*)alloc(KNOW + 1);
    int* off3 = (int*)alloc(ITEM + 1);
    int* es1  = (int*)alloc(E1);
    int* es2  = (int*)alloc(E2);
    int* es3  = (int*)alloc(E2);
    float* krowP = alloc((size_t)CH * BB * KNOW);
    float* hbuf  = alloc((size_t)BB * H3);
    float* hid   = alloc((size_t)4 * BB * LAT);

    hipMemsetAsync(cnts, 0, sizeof(int) * (2 * KNOW + NTOT), stream);

    int etot = E1 + 2 * E2;
    hist3<<<(etot + 255) / 256, 256, 0, stream>>>(dst1, dst2, dst3, E1, E2, cnt1, cnt2, cnt3);
    exscan3<<<3, 1024, 0, stream>>>(cnt1, off1, cnt2, off2, cnt3, off3);
    scatter3<<<(etot + 255) / 256, 256, 0, stream>>>(src1, dst1, src2, dst2, src3, dst3,
                                                     E1, E2, cnt1, cnt2, cnt3, es1, es2, es3);

    for (int l = 0; l < LAYERS; ++l) {
        const float* Xe = (l == 0) ? exer_table : buf;
        const float* Xk = (l == 0) ? kn_table : (buf + (size_t)ITEM * D);
        zdv_ker<<<NZT, 256, 0, stream>>>(Xe, Xk, gW, gA, l, z1, z2, z3,
                                         ds1, dd1, ds2, dd2, ds3, dd3);
        int nb = NAGGU + ((l == 0) ? NKROW : 0);   // krow units ride along with layer-0 agg
        agg3c<<<nb, 256, 0, stream>>>(z1, z2, z3, ds1, dd1, ds2, dd2, ds3, dd3,
                                      off1, es1, off2, es2, off3, es3,
                                      raW1 + (size_t)l * D * D, raB1 + (size_t)l * D,
                                      raW2 + (size_t)l * D, buf,
                                      kn_rec, kn_num, p_target, krowP);
    }
    // ex = buf[:ITEM], kn = buf[ITEM:]

    hker<<<BB, 512, 0, stream>>>(buf, ans_table, p_rec, a_rec, p_target, krowP, buf + (size_t)ITEM * D, hbuf);
    hidden_gemm<<<dim3(16, 16), 256, 0, stream>>>(hbuf, actW1, actB1, vW1, vB1, hid);
    logitsvals<<<NLV + NVB, 256, 0, stream>>>(hid, actW2, actB2, vW2, vB2, (float*)d_out);
}